// Round 1
// baseline (6187.960 us; speedup 1.0000x reference)
//
#include <hip/hip_runtime.h>
#include <math.h>

#define Bb 8
#define Ss 2048
#define Ee 1024
#define BSr (Bb*Ss)

#define TQ 16
#define TK 256
#define EC 64
#define NCH (Ee/EC)     // 16
#define NT  (Ss/TK)     // 8

// ---------------- Kernel 1: QKV projection  y[r][f] = sum_e x[r][e]*W[f][e] + b[f]
// grid (Ee/64, BSr/64, 3), block 256. 64x64 C-tile, 4x4 per thread, fp32.
__global__ __launch_bounds__(256)
void qkv_gemm(const float* __restrict__ x,
              const float* __restrict__ Wq, const float* __restrict__ bq,
              const float* __restrict__ Wk, const float* __restrict__ bk,
              const float* __restrict__ Wv, const float* __restrict__ bv,
              float* __restrict__ oq, float* __restrict__ ok, float* __restrict__ ov)
{
    __shared__ float Xs[64][17];   // +1 pad: scalar compute reads conflict-free
    __shared__ float Ws[64][17];
    const int t = threadIdx.x;
    const int z = blockIdx.z;
    const float* __restrict__ W    = (z == 0) ? Wq : ((z == 1) ? Wk : Wv);
    const float* __restrict__ bias = (z == 0) ? bq : ((z == 1) ? bk : bv);
    float* __restrict__ out        = (z == 0) ? oq : ((z == 1) ? ok : ov);

    const int row0 = blockIdx.y << 6;
    const int col0 = blockIdx.x << 6;
    const int ti = t >> 4;          // 0..15 row group
    const int tj = t & 15;          // 0..15 col group
    const int lr = t >> 2;          // staging row 0..63
    const int lc = (t & 3) << 2;    // staging col {0,4,8,12}

    float acc[4][4];
    #pragma unroll
    for (int i = 0; i < 4; ++i)
        #pragma unroll
        for (int j = 0; j < 4; ++j) acc[i][j] = 0.f;

    for (int e0 = 0; e0 < Ee; e0 += 16) {
        __syncthreads();
        {
            float4 xv = *(const float4*)&x[(row0 + lr)*Ee + e0 + lc];
            float4 wv = *(const float4*)&W[(col0 + lr)*Ee + e0 + lc];
            Xs[lr][lc]   = xv.x; Xs[lr][lc+1] = xv.y; Xs[lr][lc+2] = xv.z; Xs[lr][lc+3] = xv.w;
            Ws[lr][lc]   = wv.x; Ws[lr][lc+1] = wv.y; Ws[lr][lc+2] = wv.z; Ws[lr][lc+3] = wv.w;
        }
        __syncthreads();
        #pragma unroll
        for (int ee = 0; ee < 16; ++ee) {
            float xa[4], wb[4];
            #pragma unroll
            for (int i = 0; i < 4; ++i) xa[i] = Xs[(ti<<2)+i][ee];
            #pragma unroll
            for (int j = 0; j < 4; ++j) wb[j] = Ws[(tj<<2)+j][ee];
            #pragma unroll
            for (int i = 0; i < 4; ++i)
                #pragma unroll
                for (int j = 0; j < 4; ++j)
                    acc[i][j] = fmaf(xa[i], wb[j], acc[i][j]);
        }
    }

    const float4 b4 = *(const float4*)&bias[col0 + (tj<<2)];
    #pragma unroll
    for (int i = 0; i < 4; ++i) {
        float4 o;
        o.x = acc[i][0] + b4.x;
        o.y = acc[i][1] + b4.y;
        o.z = acc[i][2] + b4.z;
        o.w = acc[i][3] + b4.w;
        *(float4*)&out[(row0 + (ti<<2) + i)*Ee + col0 + (tj<<2)] = o;
    }
}

// ---------------- Kernel 2: single-pass flash attention, fp32, online softmax.
// block = 256 thr (4 waves). TQ=16 q rows/block, TK=256 k rows/tile.
// Wave w owns score rows 4w..4w+3 (row stats via 64-lane shfl butterflies).
// LDS: qs 65.8KB + kv 69.6KB + ps 16.6KB = 152KB -> 1 block/CU.
__global__ __launch_bounds__(256)
void flash_attn(const float* __restrict__ qsrc,
                const float* __restrict__ ksrc,
                const float* __restrict__ vsrc,
                float* __restrict__ out)
{
    __shared__ float qs[TQ][1028];   // stride 1028: 16B-aligned rows
    __shared__ float kv[TK][68];     // k / v chunk staging (stride 272B: aligned + even banks)
    __shared__ float ps[TQ][260];    // P tile (fp32)
    __shared__ float f_s[TQ];
    __shared__ float l_s[TQ];

    const int t = threadIdx.x;
    const int lane = t & 63;
    const int w = t >> 6;                 // wave 0..3
    const int q0 = blockIdx.x * TQ;       // global q row
    const int kb = (q0 / Ss) * Ss;        // batch base row for k/v

    // load q tile (from d_out scratch; this block's own rows only)
    {
        const int r = t >> 4;
        const int c0 = (t & 15) << 2;
        #pragma unroll
        for (int m = 0; m < 16; ++m) {
            float4 v4 = *(const float4*)&qsrc[(q0 + r)*Ee + c0 + (m << 6)];
            *(float4*)&qs[r][c0 + (m << 6)] = v4;
        }
    }

    float4 oacc[NCH];
    #pragma unroll
    for (int i = 0; i < NCH; ++i) oacc[i] = make_float4(0.f, 0.f, 0.f, 0.f);
    float m_reg[4], l_reg[4];
    #pragma unroll
    for (int i = 0; i < 4; ++i) { m_reg[i] = -INFINITY; l_reg[i] = 0.f; }

    const int ow = t >> 4;          // out row 0..15
    const int oc = (t & 15) << 2;   // out col-in-chunk {0..60}

    for (int kt = 0; kt < NT; ++kt) {
        const int kr0 = kb + kt * TK;

        // ---- Phase A: scores S[16][256], e-chunked k staging
        float sacc[4][4];
        #pragma unroll
        for (int i = 0; i < 4; ++i)
            #pragma unroll
            for (int j = 0; j < 4; ++j) sacc[i][j] = 0.f;

        for (int ec = 0; ec < NCH; ++ec) {
            __syncthreads();
            {
                const int rr = t >> 4;
                const int cc = (t & 15) << 2;
                #pragma unroll
                for (int m = 0; m < 16; ++m) {
                    float4 v4 = *(const float4*)&ksrc[(kr0 + rr + (m<<4))*Ee + ec*EC + cc];
                    *(float4*)&kv[rr + (m<<4)][cc] = v4;
                }
            }
            __syncthreads();
            #pragma unroll 4
            for (int ee = 0; ee < EC; ee += 4) {
                float4 q4[4];
                #pragma unroll
                for (int i = 0; i < 4; ++i)
                    q4[i] = *(const float4*)&qs[(w<<2)+i][ec*EC + ee];   // wave-uniform broadcast
                #pragma unroll
                for (int j = 0; j < 4; ++j) {
                    float4 k4 = *(const float4*)&kv[lane + (j<<6)][ee];
                    #pragma unroll
                    for (int i = 0; i < 4; ++i) {
                        sacc[i][j] = fmaf(q4[i].x, k4.x, sacc[i][j]);
                        sacc[i][j] = fmaf(q4[i].y, k4.y, sacc[i][j]);
                        sacc[i][j] = fmaf(q4[i].z, k4.z, sacc[i][j]);
                        sacc[i][j] = fmaf(q4[i].w, k4.w, sacc[i][j]);
                    }
                }
            }
        }

        // ---- Phase B: online softmax update (wave w owns rows 4w+i)
        float tmax[4];
        #pragma unroll
        for (int i = 0; i < 4; ++i)
            tmax[i] = fmaxf(fmaxf(sacc[i][0], sacc[i][1]), fmaxf(sacc[i][2], sacc[i][3]));
        #pragma unroll
        for (int off = 1; off < 64; off <<= 1) {
            #pragma unroll
            for (int i = 0; i < 4; ++i)
                tmax[i] = fmaxf(tmax[i], __shfl_xor(tmax[i], off, 64));
        }
        float rs[4], fi[4];
        #pragma unroll
        for (int i = 0; i < 4; ++i) {
            float mn = fmaxf(m_reg[i], tmax[i]);
            fi[i] = __expf(m_reg[i] - mn);   // -inf -> 0 on first tile
            m_reg[i] = mn;
            float r = 0.f;
            #pragma unroll
            for (int j = 0; j < 4; ++j) {
                float p = __expf(sacc[i][j] - mn);
                ps[(w<<2)+i][lane + (j<<6)] = p;
                r += p;
            }
            rs[i] = r;
        }
        #pragma unroll
        for (int off = 1; off < 64; off <<= 1) {
            #pragma unroll
            for (int i = 0; i < 4; ++i)
                rs[i] += __shfl_xor(rs[i], off, 64);
        }
        #pragma unroll
        for (int i = 0; i < 4; ++i)
            l_reg[i] = l_reg[i] * fi[i] + rs[i];
        if (lane == 0) {
            #pragma unroll
            for (int i = 0; i < 4; ++i) {
                f_s[(w<<2)+i] = fi[i];
                l_s[(w<<2)+i] = l_reg[i];
            }
        }
        __syncthreads();   // publish ps, f_s

        // ---- Phase C: rescale + PV, e-chunked v staging (reuses kv buffer)
        const float fown = f_s[ow];
        #pragma unroll
        for (int c4 = 0; c4 < NCH; ++c4) {
            oacc[c4].x *= fown; oacc[c4].y *= fown;
            oacc[c4].z *= fown; oacc[c4].w *= fown;
        }
        for (int pc = 0; pc < NCH; ++pc) {
            __syncthreads();
            {
                const int rr = t >> 4;
                const int cc = (t & 15) << 2;
                #pragma unroll
                for (int m = 0; m < 16; ++m) {
                    float4 v4 = *(const float4*)&vsrc[(kr0 + rr + (m<<4))*Ee + pc*EC + cc];
                    *(float4*)&kv[rr + (m<<4)][cc] = v4;
                }
            }
            __syncthreads();
            float4 acc = oacc[pc];
            #pragma unroll 4
            for (int tj0 = 0; tj0 < TK; tj0 += 4) {
                float4 p4 = *(const float4*)&ps[ow][tj0];
                float4 v0 = *(const float4*)&kv[tj0+0][oc];
                float4 v1 = *(const float4*)&kv[tj0+1][oc];
                float4 v2 = *(const float4*)&kv[tj0+2][oc];
                float4 v3 = *(const float4*)&kv[tj0+3][oc];
                acc.x = fmaf(p4.x, v0.x, acc.x); acc.y = fmaf(p4.x, v0.y, acc.y);
                acc.z = fmaf(p4.x, v0.z, acc.z); acc.w = fmaf(p4.x, v0.w, acc.w);
                acc.x = fmaf(p4.y, v1.x, acc.x); acc.y = fmaf(p4.y, v1.y, acc.y);
                acc.z = fmaf(p4.y, v1.z, acc.z); acc.w = fmaf(p4.y, v1.w, acc.w);
                acc.x = fmaf(p4.z, v2.x, acc.x); acc.y = fmaf(p4.z, v2.y, acc.y);
                acc.z = fmaf(p4.z, v2.z, acc.z); acc.w = fmaf(p4.z, v2.w, acc.w);
                acc.x = fmaf(p4.w, v3.x, acc.x); acc.y = fmaf(p4.w, v3.y, acc.y);
                acc.z = fmaf(p4.w, v3.z, acc.z); acc.w = fmaf(p4.w, v3.w, acc.w);
            }
            oacc[pc] = acc;
        }
    }

    __syncthreads();
    const float linv = 1.0f / l_s[ow];
    #pragma unroll
    for (int c4 = 0; c4 < NCH; ++c4) {
        float4 o = oacc[c4];
        o.x *= linv; o.y *= linv; o.z *= linv; o.w *= linv;
        *(float4*)&out[(q0 + ow)*Ee + oc + (c4 << 6)] = o;
    }
}

extern "C" void kernel_launch(void* const* d_in, const int* in_sizes, int n_in,
                              void* d_out, int out_size, void* d_ws, size_t ws_size,
                              hipStream_t stream)
{
    (void)in_sizes; (void)n_in; (void)out_size; (void)ws_size;
    const float* x  = (const float*)d_in[0];
    const float* Wq = (const float*)d_in[1];
    const float* bq = (const float*)d_in[2];
    const float* Wk = (const float*)d_in[3];
    const float* bk = (const float*)d_in[4];
    const float* Wv = (const float*)d_in[5];
    const float* bv = (const float*)d_in[6];
    float* out  = (float*)d_out;
    float* kbuf = (float*)d_ws;                       // [BSr, Ee] fp32  (64 MB)
    float* vbuf = kbuf + (size_t)BSr * Ee;            // [BSr, Ee] fp32  (64 MB)

    // q -> d_out (scratch; flash kernel reads its own rows before overwriting)
    dim3 g1(Ee/64, BSr/64, 3);
    qkv_gemm<<<g1, 256, 0, stream>>>(x, Wq, bq, Wk, bk, Wv, bv, out, kbuf, vbuf);

    flash_attn<<<dim3(BSr/TQ), 256, 0, stream>>>(out, kbuf, vbuf, out);
}

// Round 2
// 808.350 us; speedup vs baseline: 7.6551x; 7.6551x over previous
//
#include <hip/hip_runtime.h>
#include <math.h>

typedef _Float16 f16;
typedef _Float16 f16x8 __attribute__((ext_vector_type(8)));
typedef _Float16 f16x4 __attribute__((ext_vector_type(4)));
typedef float f32x4v __attribute__((ext_vector_type(4)));

#define Bb 8
#define Ss 2048
#define Ee 1024
#define BSr (Bb*Ss)

// ---------------------------------------------------------------- helpers
__device__ __forceinline__ void gll16(const void* gp, void* lp) {
    // async global->LDS, 16B per lane, LDS dest = wave-uniform base + lane*16
    __builtin_amdgcn_global_load_lds(
        (const __attribute__((address_space(1))) unsigned int*)gp,
        (__attribute__((address_space(3))) unsigned int*)lp,
        16, 0, 0);
}

#define MFMA16(a, b, c) __builtin_amdgcn_mfma_f32_16x16x32_f16((a), (b), (c), 0, 0, 0)

// ================================================================ fast path
// Kernel A: split Wq,Wk into fp16 hi/lo planes; Wv hi only.
__global__ __launch_bounds__(256)
void split_weights(const float* __restrict__ Wq, const float* __restrict__ Wk,
                   const float* __restrict__ Wv,
                   f16* __restrict__ Wqh, f16* __restrict__ Wql,
                   f16* __restrict__ Wkh, f16* __restrict__ Wkl,
                   f16* __restrict__ Wvh)
{
    const int i = (blockIdx.x * 256 + threadIdx.x) * 4;
    float4 q = *(const float4*)&Wq[i];
    float4 k = *(const float4*)&Wk[i];
    float4 v = *(const float4*)&Wv[i];
    f16x4 qh4, ql4, kh4, kl4, vh4;
#define SPL(val, h4, l4, idx) { f16 hh = (f16)(val); h4[idx] = hh; l4[idx] = (f16)((val) - (float)hh); }
    SPL(q.x, qh4, ql4, 0) SPL(q.y, qh4, ql4, 1) SPL(q.z, qh4, ql4, 2) SPL(q.w, qh4, ql4, 3)
    SPL(k.x, kh4, kl4, 0) SPL(k.y, kh4, kl4, 1) SPL(k.z, kh4, kl4, 2) SPL(k.w, kh4, kl4, 3)
#undef SPL
    vh4[0] = (f16)v.x; vh4[1] = (f16)v.y; vh4[2] = (f16)v.z; vh4[3] = (f16)v.w;
    *(f16x4*)&Wqh[i] = qh4; *(f16x4*)&Wql[i] = ql4;
    *(f16x4*)&Wkh[i] = kh4; *(f16x4*)&Wkl[i] = kl4;
    *(f16x4*)&Wvh[i] = vh4;
}

// Kernel B: projection GEMM. y = x * W^T + b. M=16384, N=1024, K=1024.
// z=0 -> q (split out), z=1 -> k (split out), z=2 -> v (fp16, written transposed per batch).
// 128x128 tile, BK=32, 4 waves (2x2), per-wave 4x4 tiles of 16x16x32 MFMA.
__global__ __launch_bounds__(256)
void proj_gemm(const float* __restrict__ x,
               const f16* __restrict__ Wqh, const f16* __restrict__ Wql,
               const f16* __restrict__ Wkh, const f16* __restrict__ Wkl,
               const f16* __restrict__ Wvh,
               const float* __restrict__ bq, const float* __restrict__ bk,
               const float* __restrict__ bv,
               f16* __restrict__ qh, f16* __restrict__ ql,
               f16* __restrict__ kh, f16* __restrict__ kl,
               f16* __restrict__ vT)
{
    __shared__ f16 Ah[128][32];
    __shared__ f16 Al[128][32];
    __shared__ f16 Bh[128][32];
    __shared__ f16 Bl[128][32];

    const int z = blockIdx.z;
    const bool splitpath = (z < 2);
    const f16* __restrict__ Wh = (z == 0) ? Wqh : ((z == 1) ? Wkh : Wvh);
    const f16* __restrict__ Wl = (z == 0) ? Wql : Wkl;   // unused for z==2
    const float* __restrict__ bias = (z == 0) ? bq : ((z == 1) ? bk : bv);

    const int row0 = blockIdx.y * 128;   // x rows
    const int col0 = blockIdx.x * 128;   // output features

    const int t = threadIdx.x;
    const int lane = t & 63;
    const int w = t >> 6;
    const int wr = w >> 1, wc = w & 1;
    const int lr = lane & 15;
    const int kq = (lane >> 4) << 3;

    // x reg-staging map: thread -> (row, 16-wide k half)
    const int sar = t >> 1;
    const int sac = (t & 1) * 16;
    // global_load_lds map for W planes: linear byte L = w*2048 + c*1024 + lane*16
    const int rB = w * 32 + (lane >> 2);      // +16 per call c
    const int eB = (lane & 3) * 8;            // f16 elements

    f32x4v acc[4][4];
    #pragma unroll
    for (int i = 0; i < 4; ++i)
        #pragma unroll
        for (int j = 0; j < 4; ++j) acc[i][j] = (f32x4v)0.f;

    const float* xs_base = &x[(row0 + sar) * Ee + sac];
    const f16* gBh = Wh + (col0 + rB) * Ee + eB;
    const f16* gBl = Wl + (col0 + rB) * Ee + eB;

    for (int k0 = 0; k0 < Ee; k0 += 32) {
        __syncthreads();
        {   // stage x -> Ah/Al (convert fp32 -> hi/lo fp16)
            const float* xs = xs_base + k0;
            float4 v0 = *(const float4*)&xs[0];
            float4 v1 = *(const float4*)&xs[4];
            float4 v2 = *(const float4*)&xs[8];
            float4 v3 = *(const float4*)&xs[12];
            f16x8 h0, h1, l0, l1;
#define CVT(h, l, idx, val) { f16 hh = (f16)(val); h[idx] = hh; l[idx] = (f16)((val) - (float)hh); }
            CVT(h0, l0, 0, v0.x) CVT(h0, l0, 1, v0.y) CVT(h0, l0, 2, v0.z) CVT(h0, l0, 3, v0.w)
            CVT(h0, l0, 4, v1.x) CVT(h0, l0, 5, v1.y) CVT(h0, l0, 6, v1.z) CVT(h0, l0, 7, v1.w)
            CVT(h1, l1, 0, v2.x) CVT(h1, l1, 1, v2.y) CVT(h1, l1, 2, v2.z) CVT(h1, l1, 3, v2.w)
            CVT(h1, l1, 4, v3.x) CVT(h1, l1, 5, v3.y) CVT(h1, l1, 6, v3.z) CVT(h1, l1, 7, v3.w)
#undef CVT
            *(f16x8*)&Ah[sar][sac]     = h0;
            *(f16x8*)&Ah[sar][sac + 8] = h1;
            *(f16x8*)&Al[sar][sac]     = l0;
            *(f16x8*)&Al[sar][sac + 8] = l1;
        }
        // stage W planes via global_load_lds (each wave: 2 calls of 1024B per plane)
        #pragma unroll
        for (int c = 0; c < 2; ++c) {
            gll16(gBh + (size_t)c * 16 * Ee + k0, &Bh[0][0] + w * 1024 + c * 512);
            if (splitpath)
                gll16(gBl + (size_t)c * 16 * Ee + k0, &Bl[0][0] + w * 1024 + c * 512);
        }
        __syncthreads();

        f16x8 fah[4], fbh[4];
        #pragma unroll
        for (int i = 0; i < 4; ++i) fah[i] = *(const f16x8*)&Ah[wr * 64 + i * 16 + lr][kq];
        #pragma unroll
        for (int j = 0; j < 4; ++j) fbh[j] = *(const f16x8*)&Bh[wc * 64 + j * 16 + lr][kq];
        #pragma unroll
        for (int i = 0; i < 4; ++i)
            #pragma unroll
            for (int j = 0; j < 4; ++j)
                acc[i][j] = MFMA16(fah[i], fbh[j], acc[i][j]);
        if (splitpath) {
            f16x8 fal[4], fbl[4];
            #pragma unroll
            for (int i = 0; i < 4; ++i) fal[i] = *(const f16x8*)&Al[wr * 64 + i * 16 + lr][kq];
            #pragma unroll
            for (int j = 0; j < 4; ++j) fbl[j] = *(const f16x8*)&Bl[wc * 64 + j * 16 + lr][kq];
            #pragma unroll
            for (int i = 0; i < 4; ++i)
                #pragma unroll
                for (int j = 0; j < 4; ++j) {
                    acc[i][j] = MFMA16(fah[i], fbl[j], acc[i][j]);
                    acc[i][j] = MFMA16(fal[i], fbh[j], acc[i][j]);
                }
        }
    }

    // epilogue
    if (splitpath) {
        f16* __restrict__ oh = (z == 0) ? qh : kh;
        f16* __restrict__ ol = (z == 0) ? ql : kl;
        #pragma unroll
        for (int i = 0; i < 4; ++i) {
            #pragma unroll
            for (int j = 0; j < 4; ++j) {
                const int col = col0 + wc * 64 + j * 16 + lr;
                const float b = bias[col];
                #pragma unroll
                for (int r = 0; r < 4; ++r) {
                    const int row = row0 + wr * 64 + i * 16 + (lane >> 4) * 4 + r;
                    const float vv = acc[i][j][r] + b;
                    const f16 hh = (f16)vv;
                    oh[(size_t)row * Ee + col] = hh;
                    ol[(size_t)row * Ee + col] = (f16)(vv - (float)hh);
                }
            }
        }
    } else {
        // v: write transposed per batch: vT[b][e][s]
        #pragma unroll
        for (int i = 0; i < 4; ++i) {
            #pragma unroll
            for (int j = 0; j < 4; ++j) {
                const int e = col0 + wc * 64 + j * 16 + lr;
                const float b = bias[e];
                const int srow = row0 + wr * 64 + i * 16 + (lane >> 4) * 4; // 4 consecutive seq
                const int bb = srow >> 11;
                const int s = srow & 2047;
                f16x4 pk;
                #pragma unroll
                for (int r = 0; r < 4; ++r) pk[r] = (f16)(acc[i][j][r] + b);
                *(f16x4*)&vT[((size_t)bb * Ee + e) * Ss + s] = pk;
            }
        }
    }
}

// Kernel C: scores S = q * k^T (per batch). M=N=2048, K=1024, 3-pass split.
// grid (16, 16, 2): x=k-tile, y=q-tile, z=batch-in-chunk.
__global__ __launch_bounds__(256)
void score_gemm(const f16* __restrict__ qh, const f16* __restrict__ ql,
                const f16* __restrict__ kh, const f16* __restrict__ kl,
                float* __restrict__ Sbuf, int batch0)
{
    __shared__ f16 Qh[128][32];
    __shared__ f16 Ql[128][32];
    __shared__ f16 Kh[128][32];
    __shared__ f16 Kl[128][32];

    const int zb = blockIdx.z;
    const int b = batch0 + zb;
    const int bm = blockIdx.y, bn = blockIdx.x;

    const int t = threadIdx.x;
    const int lane = t & 63;
    const int w = t >> 6;
    const int wr = w >> 1, wc = w & 1;
    const int lr = lane & 15;
    const int kq = (lane >> 4) << 3;

    const int rS = w * 32 + (lane >> 2);
    const int eS = (lane & 3) * 8;

    const f16* gAh = qh + ((size_t)b * Ss + bm * 128 + rS) * Ee + eS;
    const f16* gAl = ql + ((size_t)b * Ss + bm * 128 + rS) * Ee + eS;
    const f16* gBh = kh + ((size_t)b * Ss + bn * 128 + rS) * Ee + eS;
    const f16* gBl = kl + ((size_t)b * Ss + bn * 128 + rS) * Ee + eS;

    f32x4v acc[4][4];
    #pragma unroll
    for (int i = 0; i < 4; ++i)
        #pragma unroll
        for (int j = 0; j < 4; ++j) acc[i][j] = (f32x4v)0.f;

    for (int k0 = 0; k0 < Ee; k0 += 32) {
        __syncthreads();
        #pragma unroll
        for (int c = 0; c < 2; ++c) {
            const size_t go = (size_t)c * 16 * Ee + k0;
            f16* lo = (f16*)0 + w * 1024 + c * 512;   // element offset helper
            gll16(gAh + go, &Qh[0][0] + (size_t)(lo - (f16*)0));
            gll16(gAl + go, &Ql[0][0] + (size_t)(lo - (f16*)0));
            gll16(gBh + go, &Kh[0][0] + (size_t)(lo - (f16*)0));
            gll16(gBl + go, &Kl[0][0] + (size_t)(lo - (f16*)0));
        }
        __syncthreads();

        f16x8 fah[4], fal[4], fbh[4], fbl[4];
        #pragma unroll
        for (int i = 0; i < 4; ++i) {
            fah[i] = *(const f16x8*)&Qh[wr * 64 + i * 16 + lr][kq];
            fal[i] = *(const f16x8*)&Ql[wr * 64 + i * 16 + lr][kq];
            fbh[i] = *(const f16x8*)&Kh[wc * 64 + i * 16 + lr][kq];
            fbl[i] = *(const f16x8*)&Kl[wc * 64 + i * 16 + lr][kq];
        }
        #pragma unroll
        for (int i = 0; i < 4; ++i)
            #pragma unroll
            for (int j = 0; j < 4; ++j) {
                acc[i][j] = MFMA16(fah[i], fbh[j], acc[i][j]);
                acc[i][j] = MFMA16(fah[i], fbl[j], acc[i][j]);
                acc[i][j] = MFMA16(fal[i], fbh[j], acc[i][j]);
            }
    }

    // write S (fp32), row stride 2048
    #pragma unroll
    for (int i = 0; i < 4; ++i) {
        #pragma unroll
        for (int j = 0; j < 4; ++j) {
            const int col = bn * 128 + wc * 64 + j * 16 + lr;
            #pragma unroll
            for (int r = 0; r < 4; ++r) {
                const int row = zb * Ss + bm * 128 + wr * 64 + i * 16 + (lane >> 4) * 4 + r;
                Sbuf[(size_t)row * 2048 + col] = acc[i][j][r];
            }
        }
    }
}

// Kernel D: row softmax, in-place: S fp32 row -> normalized P fp16 in first half.
__global__ __launch_bounds__(256)
void softmax_rows(float* __restrict__ Sbuf)
{
    __shared__ float red[8];
    const int t = threadIdx.x;
    const int w = t >> 6;
    float* Srow = Sbuf + (size_t)blockIdx.x * 2048;

    float4 a = *(const float4*)&Srow[t * 8];
    float4 c = *(const float4*)&Srow[t * 8 + 4];
    float v[8] = {a.x, a.y, a.z, a.w, c.x, c.y, c.z, c.w};

    float m = v[0];
    #pragma unroll
    for (int i = 1; i < 8; ++i) m = fmaxf(m, v[i]);
    #pragma unroll
    for (int off = 1; off < 64; off <<= 1) m = fmaxf(m, __shfl_xor(m, off, 64));
    if ((t & 63) == 0) red[w] = m;
    __syncthreads();
    m = fmaxf(fmaxf(red[0], red[1]), fmaxf(red[2], red[3]));

    float e[8], s = 0.f;
    #pragma unroll
    for (int i = 0; i < 8; ++i) { e[i] = expf(v[i] - m); s += e[i]; }
    #pragma unroll
    for (int off = 1; off < 64; off <<= 1) s += __shfl_xor(s, off, 64);
    if ((t & 63) == 0) red[4 + w] = s;
    __syncthreads();
    s = red[4] + red[5] + red[6] + red[7];

    const float inv = 1.0f / s;
    f16x8 pk;
    #pragma unroll
    for (int i = 0; i < 8; ++i) pk[i] = (f16)(e[i] * inv);
    *(f16x8*)(((f16*)Srow) + t * 8) = pk;
}

// Kernel E: O = P * v. M=2048, N=1024, K=2048. A = P (fp16, row stride 4096),
// B = vT (fp16, [b][e][s], K contiguous). grid (8, 16, 2).
__global__ __launch_bounds__(256)
void pv_gemm(const float* __restrict__ Sbuf, const f16* __restrict__ vT,
             float* __restrict__ out, int batch0)
{
    __shared__ f16 Pt[128][32];
    __shared__ f16 Vt[128][32];

    const int zb = blockIdx.z;
    const int b = batch0 + zb;
    const int bm = blockIdx.y;   // q-row tile
    const int bn = blockIdx.x;   // E tile

    const int t = threadIdx.x;
    const int lane = t & 63;
    const int w = t >> 6;
    const int wr = w >> 1, wc = w & 1;
    const int lr = lane & 15;
    const int kq = (lane >> 4) << 3;

    const int rS = w * 32 + (lane >> 2);
    const int eS = (lane & 3) * 8;

    const f16* Pbase = (const f16*)Sbuf;
    const f16* gA = Pbase + ((size_t)(zb * Ss + bm * 128 + rS)) * 4096 + eS;
    const f16* gB = vT + ((size_t)b * Ee + bn * 128 + rS) * Ss + eS;

    f32x4v acc[4][4];
    #pragma unroll
    for (int i = 0; i < 4; ++i)
        #pragma unroll
        for (int j = 0; j < 4; ++j) acc[i][j] = (f32x4v)0.f;

    for (int k0 = 0; k0 < Ss; k0 += 32) {
        __syncthreads();
        #pragma unroll
        for (int c = 0; c < 2; ++c) {
            gll16(gA + (size_t)c * 16 * 4096 + k0, &Pt[0][0] + w * 1024 + c * 512);
            gll16(gB + (size_t)c * 16 * Ss + k0,   &Vt[0][0] + w * 1024 + c * 512);
        }
        __syncthreads();

        f16x8 fa[4], fb[4];
        #pragma unroll
        for (int i = 0; i < 4; ++i) {
            fa[i] = *(const f16x8*)&Pt[wr * 64 + i * 16 + lr][kq];
            fb[i] = *(const f16x8*)&Vt[wc * 64 + i * 16 + lr][kq];
        }
        #pragma unroll
        for (int i = 0; i < 4; ++i)
            #pragma unroll
            for (int j = 0; j < 4; ++j)
                acc[i][j] = MFMA16(fa[i], fb[j], acc[i][j]);
    }

    #pragma unroll
    for (int i = 0; i < 4; ++i) {
        #pragma unroll
        for (int j = 0; j < 4; ++j) {
            const int col = bn * 128 + wc * 64 + j * 16 + lr;
            #pragma unroll
            for (int r = 0; r < 4; ++r) {
                const int row = bm * 128 + wr * 64 + i * 16 + (lane >> 4) * 4 + r;
                out[((size_t)b * Ss + row) * Ee + col] = acc[i][j][r];
            }
        }
    }
}

// ================================================================ legacy path (round-1, fp32)
#define TQ 16
#define TK 256
#define EC 64
#define NCH (Ee/EC)
#define NT  (Ss/TK)

__global__ __launch_bounds__(256)
void qkv_gemm(const float* __restrict__ x,
              const float* __restrict__ Wq, const float* __restrict__ bq,
              const float* __restrict__ Wk, const float* __restrict__ bk,
              const float* __restrict__ Wv, const float* __restrict__ bv,
              float* __restrict__ oq, float* __restrict__ ok, float* __restrict__ ov)
{
    __shared__ float Xs[64][17];
    __shared__ float Ws[64][17];
    const int t = threadIdx.x;
    const int z = blockIdx.z;
    const float* __restrict__ W    = (z == 0) ? Wq : ((z == 1) ? Wk : Wv);
    const float* __restrict__ bias = (z == 0) ? bq : ((z == 1) ? bk : bv);
    float* __restrict__ out        = (z == 0) ? oq : ((z == 1) ? ok : ov);

    const int row0 = blockIdx.y << 6;
    const int col0 = blockIdx.x << 6;
    const int ti = t >> 4;
    const int tj = t & 15;
    const int lr = t >> 2;
    const int lc = (t & 3) << 2;

    float acc[4][4];
    #pragma unroll
    for (int i = 0; i < 4; ++i)
        #pragma unroll
        for (int j = 0; j < 4; ++j) acc[i][j] = 0.f;

    for (int e0 = 0; e0 < Ee; e0 += 16) {
        __syncthreads();
        {
            float4 xv = *(const float4*)&x[(row0 + lr)*Ee + e0 + lc];
            float4 wv = *(const float4*)&W[(col0 + lr)*Ee + e0 + lc];
            Xs[lr][lc]   = xv.x; Xs[lr][lc+1] = xv.y; Xs[lr][lc+2] = xv.z; Xs[lr][lc+3] = xv.w;
            Ws[lr][lc]   = wv.x; Ws[lr][lc+1] = wv.y; Ws[lr][lc+2] = wv.z; Ws[lr][lc+3] = wv.w;
        }
        __syncthreads();
        #pragma unroll
        for (int ee = 0; ee < 16; ++ee) {
            float xa[4], wb[4];
            #pragma unroll
            for (int i = 0; i < 4; ++i) xa[i] = Xs[(ti<<2)+i][ee];
            #pragma unroll
            for (int j = 0; j < 4; ++j) wb[j] = Ws[(tj<<2)+j][ee];
            #pragma unroll
            for (int i = 0; i < 4; ++i)
                #pragma unroll
                for (int j = 0; j < 4; ++j)
                    acc[i][j] = fmaf(xa[i], wb[j], acc[i][j]);
        }
    }

    const float4 b4 = *(const float4*)&bias[col0 + (tj<<2)];
    #pragma unroll
    for (int i = 0; i < 4; ++i) {
        float4 o;
        o.x = acc[i][0] + b4.x;
        o.y = acc[i][1] + b4.y;
        o.z = acc[i][2] + b4.z;
        o.w = acc[i][3] + b4.w;
        *(float4*)&out[(row0 + (ti<<2) + i)*Ee + col0 + (tj<<2)] = o;
    }
}

__global__ __launch_bounds__(256)
void flash_attn(const float* __restrict__ qsrc,
                const float* __restrict__ ksrc,
                const float* __restrict__ vsrc,
                float* __restrict__ out)
{
    __shared__ float qs[TQ][1028];
    __shared__ float kv[TK][68];
    __shared__ float ps[TQ][260];
    __shared__ float f_s[TQ];
    __shared__ float l_s[TQ];

    const int t = threadIdx.x;
    const int lane = t & 63;
    const int w = t >> 6;
    const int q0 = blockIdx.x * TQ;
    const int kb = (q0 / Ss) * Ss;

    {
        const int r = t >> 4;
        const int c0 = (t & 15) << 2;
        #pragma unroll
        for (int m = 0; m < 16; ++m) {
            float4 v4 = *(const float4*)&qsrc[(q0 + r)*Ee + c0 + (m << 6)];
            *(float4*)&qs[r][c0 + (m << 6)] = v4;
        }
    }

    float4 oacc[NCH];
    #pragma unroll
    for (int i = 0; i < NCH; ++i) oacc[i] = make_float4(0.f, 0.f, 0.f, 0.f);
    float m_reg[4], l_reg[4];
    #pragma unroll
    for (int i = 0; i < 4; ++i) { m_reg[i] = -INFINITY; l_reg[i] = 0.f; }

    const int ow = t >> 4;
    const int oc = (t & 15) << 2;

    for (int kt = 0; kt < NT; ++kt) {
        const int kr0 = kb + kt * TK;

        float sacc[4][4];
        #pragma unroll
        for (int i = 0; i < 4; ++i)
            #pragma unroll
            for (int j = 0; j < 4; ++j) sacc[i][j] = 0.f;

        for (int ec = 0; ec < NCH; ++ec) {
            __syncthreads();
            {
                const int rr = t >> 4;
                const int cc = (t & 15) << 2;
                #pragma unroll
                for (int m = 0; m < 16; ++m) {
                    float4 v4 = *(const float4*)&ksrc[(kr0 + rr + (m<<4))*Ee + ec*EC + cc];
                    *(float4*)&kv[rr + (m<<4)][cc] = v4;
                }
            }
            __syncthreads();
            #pragma unroll 4
            for (int ee = 0; ee < EC; ee += 4) {
                float4 q4[4];
                #pragma unroll
                for (int i = 0; i < 4; ++i)
                    q4[i] = *(const float4*)&qs[(w<<2)+i][ec*EC + ee];
                #pragma unroll
                for (int j = 0; j < 4; ++j) {
                    float4 k4 = *(const float4*)&kv[lane + (j<<6)][ee];
                    #pragma unroll
                    for (int i = 0; i < 4; ++i) {
                        sacc[i][j] = fmaf(q4[i].x, k4.x, sacc[i][j]);
                        sacc[i][j] = fmaf(q4[i].y, k4.y, sacc[i][j]);
                        sacc[i][j] = fmaf(q4[i].z, k4.z, sacc[i][j]);
                        sacc[i][j] = fmaf(q4[i].w, k4.w, sacc[i][j]);
                    }
                }
            }
        }

        float tmax[4];
        #pragma unroll
        for (int i = 0; i < 4; ++i)
            tmax[i] = fmaxf(fmaxf(sacc[i][0], sacc[i][1]), fmaxf(sacc[i][2], sacc[i][3]));
        #pragma unroll
        for (int off = 1; off < 64; off <<= 1) {
            #pragma unroll
            for (int i = 0; i < 4; ++i)
                tmax[i] = fmaxf(tmax[i], __shfl_xor(tmax[i], off, 64));
        }
        float rs[4], fi[4];
        #pragma unroll
        for (int i = 0; i < 4; ++i) {
            float mn = fmaxf(m_reg[i], tmax[i]);
            fi[i] = __expf(m_reg[i] - mn);
            m_reg[i] = mn;
            float r = 0.f;
            #pragma unroll
            for (int j = 0; j < 4; ++j) {
                float p = __expf(sacc[i][j] - mn);
                ps[(w<<2)+i][lane + (j<<6)] = p;
                r += p;
            }
            rs[i] = r;
        }
        #pragma unroll
        for (int off = 1; off < 64; off <<= 1) {
            #pragma unroll
            for (int i = 0; i < 4; ++i)
                rs[i] += __shfl_xor(rs[i], off, 64);
        }
        #pragma unroll
        for (int i = 0; i < 4; ++i)
            l_reg[i] = l_reg[i] * fi[i] + rs[i];
        if (lane == 0) {
            #pragma unroll
            for (int i = 0; i < 4; ++i) {
                f_s[(w<<2)+i] = fi[i];
                l_s[(w<<2)+i] = l_reg[i];
            }
        }
        __syncthreads();

        const float fown = f_s[ow];
        #pragma unroll
        for (int c4 = 0; c4 < NCH; ++c4) {
            oacc[c4].x *= fown; oacc[c4].y *= fown;
            oacc[c4].z *= fown; oacc[c4].w *= fown;
        }
        for (int pc = 0; pc < NCH; ++pc) {
            __syncthreads();
            {
                const int rr = t >> 4;
                const int cc = (t & 15) << 2;
                #pragma unroll
                for (int m = 0; m < 16; ++m) {
                    float4 v4 = *(const float4*)&vsrc[(kr0 + rr + (m<<4))*Ee + pc*EC + cc];
                    *(float4*)&kv[rr + (m<<4)][cc] = v4;
                }
            }
            __syncthreads();
            float4 acc = oacc[pc];
            #pragma unroll 4
            for (int tj0 = 0; tj0 < TK; tj0 += 4) {
                float4 p4 = *(const float4*)&ps[ow][tj0];
                float4 v0 = *(const float4*)&kv[tj0+0][oc];
                float4 v1 = *(const float4*)&kv[tj0+1][oc];
                float4 v2 = *(const float4*)&kv[tj0+2][oc];
                float4 v3 = *(const float4*)&kv[tj0+3][oc];
                acc.x = fmaf(p4.x, v0.x, acc.x); acc.y = fmaf(p4.x, v0.y, acc.y);
                acc.z = fmaf(p4.x, v0.z, acc.z); acc.w = fmaf(p4.x, v0.w, acc.w);
                acc.x = fmaf(p4.y, v1.x, acc.x); acc.y = fmaf(p4.y, v1.y, acc.y);
                acc.z = fmaf(p4.y, v1.z, acc.z); acc.w = fmaf(p4.y, v1.w, acc.w);
                acc.x = fmaf(p4.z, v2.x, acc.x); acc.y = fmaf(p4.z, v2.y, acc.y);
                acc.z = fmaf(p4.z, v2.z, acc.z); acc.w = fmaf(p4.z, v2.w, acc.w);
                acc.x = fmaf(p4.w, v3.x, acc.x); acc.y = fmaf(p4.w, v3.y, acc.y);
                acc.z = fmaf(p4.w, v3.z, acc.z); acc.w = fmaf(p4.w, v3.w, acc.w);
            }
            oacc[pc] = acc;
        }
    }

    __syncthreads();
    const float linv = 1.0f / l_s[ow];
    #pragma unroll
    for (int c4 = 0; c4 < NCH; ++c4) {
        float4 o = oacc[c4];
        o.x *= linv; o.y *= linv; o.z *= linv; o.w *= linv;
        *(float4*)&out[(q0 + ow)*Ee + oc + (c4 << 6)] = o;
    }
}

// ================================================================ launch
extern "C" void kernel_launch(void* const* d_in, const int* in_sizes, int n_in,
                              void* d_out, int out_size, void* d_ws, size_t ws_size,
                              hipStream_t stream)
{
    (void)in_sizes; (void)n_in; (void)out_size;
    const float* x  = (const float*)d_in[0];
    const float* Wq = (const float*)d_in[1];
    const float* bq = (const float*)d_in[2];
    const float* Wk = (const float*)d_in[3];
    const float* bk = (const float*)d_in[4];
    const float* Wv = (const float*)d_in[5];
    const float* bv = (const float*)d_in[6];
    float* out = (float*)d_out;

    // fast-path workspace layout (bytes):
    //   [0, 32M)        : Sbuf (4096 rows x 2048 fp32) per 2-batch chunk; P fp16 in-place
    //   [32M, 42M)      : W planes (Wqh,Wql,Wkh,Wkl,Wvh; 1024x1024 fp16 each)
    //   [42M, 170M)     : qh, ql, kh, kl (16384x1024 fp16 each)
    //   [170M, 202M)    : vT (8 x 1024 x 2048 fp16)
    const size_t S_OFF  = 0;
    const size_t W_OFF  = 33554432ull;
    const size_t WPL    = 2097152ull;       // bytes per W plane
    const size_t Q_OFF  = W_OFF + 5 * WPL;  // 44040192
    const size_t QPL    = 33554432ull;      // bytes per q/k plane
    const size_t VT_OFF = Q_OFF + 4 * QPL;  // 178257920
    const size_t NEED   = VT_OFF + 33554432ull;  // 211812352

    if (ws_size >= NEED) {
        float* Sbuf = (float*)((char*)d_ws + S_OFF);
        f16* Wqh = (f16*)((char*)d_ws + W_OFF);
        f16* Wql = Wqh + 1048576;
        f16* Wkh = Wqh + 2 * 1048576;
        f16* Wkl = Wqh + 3 * 1048576;
        f16* Wvh = Wqh + 4 * 1048576;
        f16* qh = (f16*)((char*)d_ws + Q_OFF);
        f16* ql = qh + 16777216;
        f16* kh = qh + 2 * 16777216;
        f16* kl = qh + 3 * 16777216;
        f16* vT = (f16*)((char*)d_ws + VT_OFF);

        split_weights<<<1024, 256, 0, stream>>>(Wq, Wk, Wv, Wqh, Wql, Wkh, Wkl, Wvh);
        proj_gemm<<<dim3(8, 128, 3), 256, 0, stream>>>(
            x, Wqh, Wql, Wkh, Wkl, Wvh, bq, bk, bv, qh, ql, kh, kl, vT);
        for (int c = 0; c < 4; ++c) {
            score_gemm<<<dim3(16, 16, 2), 256, 0, stream>>>(qh, ql, kh, kl, Sbuf, 2 * c);
            softmax_rows<<<4096, 256, 0, stream>>>(Sbuf);
            pv_gemm<<<dim3(8, 16, 2), 256, 0, stream>>>(Sbuf, vT, out, 2 * c);
        }
    } else {
        // legacy fp32 path (needs 128 MB ws)
        float* kbuf = (float*)d_ws;
        float* vbuf = kbuf + (size_t)BSr * Ee;
        dim3 g1(Ee / 64, BSr / 64, 3);
        qkv_gemm<<<g1, 256, 0, stream>>>(x, Wq, bq, Wk, bk, Wv, bv, out, kbuf, vbuf);
        flash_attn<<<dim3(BSr / TQ), 256, 0, stream>>>(out, kbuf, vbuf, out);
    }
}

// Round 3
// 775.371 us; speedup vs baseline: 7.9806x; 1.0425x over previous
//
#include <hip/hip_runtime.h>
#include <math.h>

typedef _Float16 f16;
typedef _Float16 f16x8 __attribute__((ext_vector_type(8)));
typedef _Float16 f16x4 __attribute__((ext_vector_type(4)));
typedef float f32x4v __attribute__((ext_vector_type(4)));

#define Bb 8
#define Ss 2048
#define Ee 1024
#define BSr (Bb*Ss)

// ---------------------------------------------------------------- helpers
__device__ __forceinline__ void gll16(const void* gp, void* lp) {
    // async global->LDS, 16B per lane, LDS dest = wave-uniform base + lane*16
    __builtin_amdgcn_global_load_lds(
        (const __attribute__((address_space(1))) unsigned int*)gp,
        (__attribute__((address_space(3))) unsigned int*)lp,
        16, 0, 0);
}

#define MFMA16(a, b, c) __builtin_amdgcn_mfma_f32_16x16x32_f16((a), (b), (c), 0, 0, 0)

// ================================================================ fast path
// Kernel A1: split Wq,Wk into fp16 hi/lo planes; Wv hi only.
__global__ __launch_bounds__(256)
void split_weights(const float* __restrict__ Wq, const float* __restrict__ Wk,
                   const float* __restrict__ Wv,
                   f16* __restrict__ Wqh, f16* __restrict__ Wql,
                   f16* __restrict__ Wkh, f16* __restrict__ Wkl,
                   f16* __restrict__ Wvh)
{
    const int i = (blockIdx.x * 256 + threadIdx.x) * 4;
    float4 q = *(const float4*)&Wq[i];
    float4 k = *(const float4*)&Wk[i];
    float4 v = *(const float4*)&Wv[i];
    f16x4 qh4, ql4, kh4, kl4, vh4;
#define SPL(val, h4, l4, idx) { f16 hh = (f16)(val); h4[idx] = hh; l4[idx] = (f16)((val) - (float)hh); }
    SPL(q.x, qh4, ql4, 0) SPL(q.y, qh4, ql4, 1) SPL(q.z, qh4, ql4, 2) SPL(q.w, qh4, ql4, 3)
    SPL(k.x, kh4, kl4, 0) SPL(k.y, kh4, kl4, 1) SPL(k.z, kh4, kl4, 2) SPL(k.w, kh4, kl4, 3)
#undef SPL
    vh4[0] = (f16)v.x; vh4[1] = (f16)v.y; vh4[2] = (f16)v.z; vh4[3] = (f16)v.w;
    *(f16x4*)&Wqh[i] = qh4; *(f16x4*)&Wql[i] = ql4;
    *(f16x4*)&Wkh[i] = kh4; *(f16x4*)&Wkl[i] = kl4;
    *(f16x4*)&Wvh[i] = vh4;
}

// Kernel A2: split x into fp16 hi/lo planes (stored in d_out scratch).
__global__ __launch_bounds__(256)
void split_x(const float* __restrict__ x, f16* __restrict__ xh, f16* __restrict__ xl)
{
    const int i = (blockIdx.x * 256 + threadIdx.x) * 4;
    float4 v = *(const float4*)&x[i];
    f16x4 h4, l4;
#define SPL(val, idx) { f16 hh = (f16)(val); h4[idx] = hh; l4[idx] = (f16)((val) - (float)hh); }
    SPL(v.x, 0) SPL(v.y, 1) SPL(v.z, 2) SPL(v.w, 3)
#undef SPL
    *(f16x4*)&xh[i] = h4;
    *(f16x4*)&xl[i] = l4;
}

// Kernel B: projection GEMM. y = x * W^T + b. M=16384, N=1024, K=1024.
// grid (24, 128): bx -> (col 0..7, z 0..2), by -> row tile. 24 consecutive
// blocks share one x row-tile -> L2/L3-hot x. All operands via global_load_lds.
// z=0 -> q (hi/lo split out), z=1 -> k (split out), z=2 -> v (fp16, transposed).
__global__ __launch_bounds__(256)
void proj_gemm(const f16* __restrict__ xh, const f16* __restrict__ xl,
               const f16* __restrict__ Wqh, const f16* __restrict__ Wql,
               const f16* __restrict__ Wkh, const f16* __restrict__ Wkl,
               const f16* __restrict__ Wvh,
               const float* __restrict__ bq, const float* __restrict__ bk,
               const float* __restrict__ bv,
               f16* __restrict__ qh, f16* __restrict__ ql,
               f16* __restrict__ kh, f16* __restrict__ kl,
               f16* __restrict__ vT)
{
    __shared__ f16 Ah[128][32];
    __shared__ f16 Al[128][32];
    __shared__ f16 Bh[128][32];
    __shared__ f16 Bl[128][32];

    const int bx = blockIdx.x;
    const int z = bx >> 3;               // 0,1,2
    const bool splitpath = (z < 2);
    const f16* __restrict__ Wh = (z == 0) ? Wqh : ((z == 1) ? Wkh : Wvh);
    const f16* __restrict__ Wl = (z == 0) ? Wql : Wkl;   // unused for z==2
    const float* __restrict__ bias = (z == 0) ? bq : ((z == 1) ? bk : bv);

    const int row0 = blockIdx.y * 128;   // x rows
    const int col0 = (bx & 7) * 128;     // output features

    const int t = threadIdx.x;
    const int lane = t & 63;
    const int w = t >> 6;
    const int wr = w >> 1, wc = w & 1;
    const int lr = lane & 15;
    const int kq = (lane >> 4) << 3;

    // global_load_lds map: per call c, wave w covers rows w*32+c*16+(lane>>2)
    const int rS = w * 32 + (lane >> 2);
    const int eS = (lane & 3) * 8;       // f16 elements (16B chunk)

    f32x4v acc[4][4];
    #pragma unroll
    for (int i = 0; i < 4; ++i)
        #pragma unroll
        for (int j = 0; j < 4; ++j) acc[i][j] = (f32x4v)0.f;

    const f16* gAh = xh + (size_t)(row0 + rS) * Ee + eS;
    const f16* gAl = xl + (size_t)(row0 + rS) * Ee + eS;
    const f16* gBh = Wh + (size_t)(col0 + rS) * Ee + eS;
    const f16* gBl = Wl + (size_t)(col0 + rS) * Ee + eS;

    for (int k0 = 0; k0 < Ee; k0 += 32) {
        __syncthreads();
        #pragma unroll
        for (int c = 0; c < 2; ++c) {
            const size_t go = (size_t)c * 16 * Ee + k0;
            const int lo = w * 1024 + c * 512;          // f16 elements
            gll16(gAh + go, &Ah[0][0] + lo);
            gll16(gBh + go, &Bh[0][0] + lo);
            if (splitpath) {
                gll16(gAl + go, &Al[0][0] + lo);
                gll16(gBl + go, &Bl[0][0] + lo);
            }
        }
        __syncthreads();

        f16x8 fah[4], fbh[4];
        #pragma unroll
        for (int i = 0; i < 4; ++i) fah[i] = *(const f16x8*)&Ah[wr * 64 + i * 16 + lr][kq];
        #pragma unroll
        for (int j = 0; j < 4; ++j) fbh[j] = *(const f16x8*)&Bh[wc * 64 + j * 16 + lr][kq];
        #pragma unroll
        for (int i = 0; i < 4; ++i)
            #pragma unroll
            for (int j = 0; j < 4; ++j)
                acc[i][j] = MFMA16(fah[i], fbh[j], acc[i][j]);
        if (splitpath) {
            f16x8 fal[4], fbl[4];
            #pragma unroll
            for (int i = 0; i < 4; ++i) fal[i] = *(const f16x8*)&Al[wr * 64 + i * 16 + lr][kq];
            #pragma unroll
            for (int j = 0; j < 4; ++j) fbl[j] = *(const f16x8*)&Bl[wc * 64 + j * 16 + lr][kq];
            #pragma unroll
            for (int i = 0; i < 4; ++i)
                #pragma unroll
                for (int j = 0; j < 4; ++j) {
                    acc[i][j] = MFMA16(fah[i], fbl[j], acc[i][j]);
                    acc[i][j] = MFMA16(fal[i], fbh[j], acc[i][j]);
                }
        }
    }

    // epilogue
    if (splitpath) {
        f16* __restrict__ oh = (z == 0) ? qh : kh;
        f16* __restrict__ ol = (z == 0) ? ql : kl;
        #pragma unroll
        for (int i = 0; i < 4; ++i) {
            #pragma unroll
            for (int j = 0; j < 4; ++j) {
                const int col = col0 + wc * 64 + j * 16 + lr;
                const float b = bias[col];
                #pragma unroll
                for (int r = 0; r < 4; ++r) {
                    const int row = row0 + wr * 64 + i * 16 + (lane >> 4) * 4 + r;
                    const float vv = acc[i][j][r] + b;
                    const f16 hh = (f16)vv;
                    oh[(size_t)row * Ee + col] = hh;
                    ol[(size_t)row * Ee + col] = (f16)(vv - (float)hh);
                }
            }
        }
    } else {
        // v: write transposed per batch: vT[b][e][s]
        #pragma unroll
        for (int i = 0; i < 4; ++i) {
            #pragma unroll
            for (int j = 0; j < 4; ++j) {
                const int e = col0 + wc * 64 + j * 16 + lr;
                const float b = bias[e];
                const int srow = row0 + wr * 64 + i * 16 + (lane >> 4) * 4; // 4 consecutive seq
                const int bb = srow >> 11;
                const int s = srow & 2047;
                f16x4 pk;
                #pragma unroll
                for (int r = 0; r < 4; ++r) pk[r] = (f16)(acc[i][j][r] + b);
                *(f16x4*)&vT[((size_t)bb * Ee + e) * Ss + s] = pk;
            }
        }
    }
}

// Kernel C: scores S = q * k^T (per batch). M=N=2048, K=1024, 3-pass split.
// grid (16, 16, 2): x=k-tile, y=q-tile, z=batch-in-chunk.
__global__ __launch_bounds__(256)
void score_gemm(const f16* __restrict__ qh, const f16* __restrict__ ql,
                const f16* __restrict__ kh, const f16* __restrict__ kl,
                float* __restrict__ Sbuf, int batch0)
{
    __shared__ f16 Qh[128][32];
    __shared__ f16 Ql[128][32];
    __shared__ f16 Kh[128][32];
    __shared__ f16 Kl[128][32];

    const int zb = blockIdx.z;
    const int b = batch0 + zb;
    const int bm = blockIdx.y, bn = blockIdx.x;

    const int t = threadIdx.x;
    const int lane = t & 63;
    const int w = t >> 6;
    const int wr = w >> 1, wc = w & 1;
    const int lr = lane & 15;
    const int kq = (lane >> 4) << 3;

    const int rS = w * 32 + (lane >> 2);
    const int eS = (lane & 3) * 8;

    const f16* gAh = qh + ((size_t)b * Ss + bm * 128 + rS) * Ee + eS;
    const f16* gAl = ql + ((size_t)b * Ss + bm * 128 + rS) * Ee + eS;
    const f16* gBh = kh + ((size_t)b * Ss + bn * 128 + rS) * Ee + eS;
    const f16* gBl = kl + ((size_t)b * Ss + bn * 128 + rS) * Ee + eS;

    f32x4v acc[4][4];
    #pragma unroll
    for (int i = 0; i < 4; ++i)
        #pragma unroll
        for (int j = 0; j < 4; ++j) acc[i][j] = (f32x4v)0.f;

    for (int k0 = 0; k0 < Ee; k0 += 32) {
        __syncthreads();
        #pragma unroll
        for (int c = 0; c < 2; ++c) {
            const size_t go = (size_t)c * 16 * Ee + k0;
            const int lo = w * 1024 + c * 512;
            gll16(gAh + go, &Qh[0][0] + lo);
            gll16(gAl + go, &Ql[0][0] + lo);
            gll16(gBh + go, &Kh[0][0] + lo);
            gll16(gBl + go, &Kl[0][0] + lo);
        }
        __syncthreads();

        f16x8 fah[4], fal[4], fbh[4], fbl[4];
        #pragma unroll
        for (int i = 0; i < 4; ++i) {
            fah[i] = *(const f16x8*)&Qh[wr * 64 + i * 16 + lr][kq];
            fal[i] = *(const f16x8*)&Ql[wr * 64 + i * 16 + lr][kq];
            fbh[i] = *(const f16x8*)&Kh[wc * 64 + i * 16 + lr][kq];
            fbl[i] = *(const f16x8*)&Kl[wc * 64 + i * 16 + lr][kq];
        }
        #pragma unroll
        for (int i = 0; i < 4; ++i)
            #pragma unroll
            for (int j = 0; j < 4; ++j) {
                acc[i][j] = MFMA16(fah[i], fbh[j], acc[i][j]);
                acc[i][j] = MFMA16(fah[i], fbl[j], acc[i][j]);
                acc[i][j] = MFMA16(fal[i], fbh[j], acc[i][j]);
            }
    }

    // write S (fp32), row stride 2048
    #pragma unroll
    for (int i = 0; i < 4; ++i) {
        #pragma unroll
        for (int j = 0; j < 4; ++j) {
            const int col = bn * 128 + wc * 64 + j * 16 + lr;
            #pragma unroll
            for (int r = 0; r < 4; ++r) {
                const int row = zb * Ss + bm * 128 + wr * 64 + i * 16 + (lane >> 4) * 4 + r;
                Sbuf[(size_t)row * 2048 + col] = acc[i][j][r];
            }
        }
    }
}

// Kernel D: row softmax, in-place: S fp32 row -> normalized P fp16 in first half.
__global__ __launch_bounds__(256)
void softmax_rows(float* __restrict__ Sbuf)
{
    __shared__ float red[8];
    const int t = threadIdx.x;
    const int w = t >> 6;
    float* Srow = Sbuf + (size_t)blockIdx.x * 2048;

    float4 a = *(const float4*)&Srow[t * 8];
    float4 c = *(const float4*)&Srow[t * 8 + 4];
    float v[8] = {a.x, a.y, a.z, a.w, c.x, c.y, c.z, c.w};

    float m = v[0];
    #pragma unroll
    for (int i = 1; i < 8; ++i) m = fmaxf(m, v[i]);
    #pragma unroll
    for (int off = 1; off < 64; off <<= 1) m = fmaxf(m, __shfl_xor(m, off, 64));
    if ((t & 63) == 0) red[w] = m;
    __syncthreads();
    m = fmaxf(fmaxf(red[0], red[1]), fmaxf(red[2], red[3]));

    float e[8], s = 0.f;
    #pragma unroll
    for (int i = 0; i < 8; ++i) { e[i] = __expf(v[i] - m); s += e[i]; }
    #pragma unroll
    for (int off = 1; off < 64; off <<= 1) s += __shfl_xor(s, off, 64);
    if ((t & 63) == 0) red[4 + w] = s;
    __syncthreads();
    s = red[4] + red[5] + red[6] + red[7];

    const float inv = 1.0f / s;
    f16x8 pk;
    #pragma unroll
    for (int i = 0; i < 8; ++i) pk[i] = (f16)(e[i] * inv);
    *(f16x8*)(((f16*)Srow) + t * 8) = pk;
}

// Kernel E: O = P * v. M=2048, N=1024, K=2048. A = P (fp16, row stride 4096),
// B = vT (fp16, [b][e][s], K contiguous). grid (8, 16, 2).
__global__ __launch_bounds__(256)
void pv_gemm(const float* __restrict__ Sbuf, const f16* __restrict__ vT,
             float* __restrict__ out, int batch0)
{
    __shared__ f16 Pt[128][32];
    __shared__ f16 Vt[128][32];

    const int zb = blockIdx.z;
    const int b = batch0 + zb;
    const int bm = blockIdx.y;   // q-row tile
    const int bn = blockIdx.x;   // E tile

    const int t = threadIdx.x;
    const int lane = t & 63;
    const int w = t >> 6;
    const int wr = w >> 1, wc = w & 1;
    const int lr = lane & 15;
    const int kq = (lane >> 4) << 3;

    const int rS = w * 32 + (lane >> 2);
    const int eS = (lane & 3) * 8;

    const f16* Pbase = (const f16*)Sbuf;
    const f16* gA = Pbase + ((size_t)(zb * Ss + bm * 128 + rS)) * 4096 + eS;
    const f16* gB = vT + ((size_t)b * Ee + bn * 128 + rS) * Ss + eS;

    f32x4v acc[4][4];
    #pragma unroll
    for (int i = 0; i < 4; ++i)
        #pragma unroll
        for (int j = 0; j < 4; ++j) acc[i][j] = (f32x4v)0.f;

    for (int k0 = 0; k0 < Ss; k0 += 32) {
        __syncthreads();
        #pragma unroll
        for (int c = 0; c < 2; ++c) {
            const int lo = w * 1024 + c * 512;
            gll16(gA + (size_t)c * 16 * 4096 + k0, &Pt[0][0] + lo);
            gll16(gB + (size_t)c * 16 * Ss + k0,   &Vt[0][0] + lo);
        }
        __syncthreads();

        f16x8 fa[4], fb[4];
        #pragma unroll
        for (int i = 0; i < 4; ++i) {
            fa[i] = *(const f16x8*)&Pt[wr * 64 + i * 16 + lr][kq];
            fb[i] = *(const f16x8*)&Vt[wc * 64 + i * 16 + lr][kq];
        }
        #pragma unroll
        for (int i = 0; i < 4; ++i)
            #pragma unroll
            for (int j = 0; j < 4; ++j)
                acc[i][j] = MFMA16(fa[i], fb[j], acc[i][j]);
    }

    #pragma unroll
    for (int i = 0; i < 4; ++i) {
        #pragma unroll
        for (int j = 0; j < 4; ++j) {
            const int col = bn * 128 + wc * 64 + j * 16 + lr;
            #pragma unroll
            for (int r = 0; r < 4; ++r) {
                const int row = bm * 128 + wr * 64 + i * 16 + (lane >> 4) * 4 + r;
                out[((size_t)b * Ss + row) * Ee + col] = acc[i][j][r];
            }
        }
    }
}

// ================================================================ legacy path (fp32 fallback)
#define TQ 16
#define TK 256
#define EC 64
#define NCH (Ee/EC)
#define NT  (Ss/TK)

__global__ __launch_bounds__(256)
void qkv_gemm(const float* __restrict__ x,
              const float* __restrict__ Wq, const float* __restrict__ bq,
              const float* __restrict__ Wk, const float* __restrict__ bk,
              const float* __restrict__ Wv, const float* __restrict__ bv,
              float* __restrict__ oq, float* __restrict__ ok, float* __restrict__ ov)
{
    __shared__ float Xs[64][17];
    __shared__ float Ws[64][17];
    const int t = threadIdx.x;
    const int z = blockIdx.z;
    const float* __restrict__ W    = (z == 0) ? Wq : ((z == 1) ? Wk : Wv);
    const float* __restrict__ bias = (z == 0) ? bq : ((z == 1) ? bk : bv);
    float* __restrict__ out        = (z == 0) ? oq : ((z == 1) ? ok : ov);

    const int row0 = blockIdx.y << 6;
    const int col0 = blockIdx.x << 6;
    const int ti = t >> 4;
    const int tj = t & 15;
    const int lr = t >> 2;
    const int lc = (t & 3) << 2;

    float acc[4][4];
    #pragma unroll
    for (int i = 0; i < 4; ++i)
        #pragma unroll
        for (int j = 0; j < 4; ++j) acc[i][j] = 0.f;

    for (int e0 = 0; e0 < Ee; e0 += 16) {
        __syncthreads();
        {
            float4 xv = *(const float4*)&x[(row0 + lr)*Ee + e0 + lc];
            float4 wv = *(const float4*)&W[(col0 + lr)*Ee + e0 + lc];
            Xs[lr][lc]   = xv.x; Xs[lr][lc+1] = xv.y; Xs[lr][lc+2] = xv.z; Xs[lr][lc+3] = xv.w;
            Ws[lr][lc]   = wv.x; Ws[lr][lc+1] = wv.y; Ws[lr][lc+2] = wv.z; Ws[lr][lc+3] = wv.w;
        }
        __syncthreads();
        #pragma unroll
        for (int ee = 0; ee < 16; ++ee) {
            float xa[4], wb[4];
            #pragma unroll
            for (int i = 0; i < 4; ++i) xa[i] = Xs[(ti<<2)+i][ee];
            #pragma unroll
            for (int j = 0; j < 4; ++j) wb[j] = Ws[(tj<<2)+j][ee];
            #pragma unroll
            for (int i = 0; i < 4; ++i)
                #pragma unroll
                for (int j = 0; j < 4; ++j)
                    acc[i][j] = fmaf(xa[i], wb[j], acc[i][j]);
        }
    }

    const float4 b4 = *(const float4*)&bias[col0 + (tj<<2)];
    #pragma unroll
    for (int i = 0; i < 4; ++i) {
        float4 o;
        o.x = acc[i][0] + b4.x;
        o.y = acc[i][1] + b4.y;
        o.z = acc[i][2] + b4.z;
        o.w = acc[i][3] + b4.w;
        *(float4*)&out[(row0 + (ti<<2) + i)*Ee + col0 + (tj<<2)] = o;
    }
}

__global__ __launch_bounds__(256)
void flash_attn(const float* __restrict__ qsrc,
                const float* __restrict__ ksrc,
                const float* __restrict__ vsrc,
                float* __restrict__ out)
{
    __shared__ float qs[TQ][1028];
    __shared__ float kv[TK][68];
    __shared__ float ps[TQ][260];
    __shared__ float f_s[TQ];
    __shared__ float l_s[TQ];

    const int t = threadIdx.x;
    const int lane = t & 63;
    const int w = t >> 6;
    const int q0 = blockIdx.x * TQ;
    const int kb = (q0 / Ss) * Ss;

    {
        const int r = t >> 4;
        const int c0 = (t & 15) << 2;
        #pragma unroll
        for (int m = 0; m < 16; ++m) {
            float4 v4 = *(const float4*)&qsrc[(q0 + r)*Ee + c0 + (m << 6)];
            *(float4*)&qs[r][c0 + (m << 6)] = v4;
        }
    }

    float4 oacc[NCH];
    #pragma unroll
    for (int i = 0; i < NCH; ++i) oacc[i] = make_float4(0.f, 0.f, 0.f, 0.f);
    float m_reg[4], l_reg[4];
    #pragma unroll
    for (int i = 0; i < 4; ++i) { m_reg[i] = -INFINITY; l_reg[i] = 0.f; }

    const int ow = t >> 4;
    const int oc = (t & 15) << 2;

    for (int kt = 0; kt < NT; ++kt) {
        const int kr0 = kb + kt * TK;

        float sacc[4][4];
        #pragma unroll
        for (int i = 0; i < 4; ++i)
            #pragma unroll
            for (int j = 0; j < 4; ++j) sacc[i][j] = 0.f;

        for (int ec = 0; ec < NCH; ++ec) {
            __syncthreads();
            {
                const int rr = t >> 4;
                const int cc = (t & 15) << 2;
                #pragma unroll
                for (int m = 0; m < 16; ++m) {
                    float4 v4 = *(const float4*)&ksrc[(kr0 + rr + (m<<4))*Ee + ec*EC + cc];
                    *(float4*)&kv[rr + (m<<4)][cc] = v4;
                }
            }
            __syncthreads();
            #pragma unroll 4
            for (int ee = 0; ee < EC; ee += 4) {
                float4 q4[4];
                #pragma unroll
                for (int i = 0; i < 4; ++i)
                    q4[i] = *(const float4*)&qs[(w<<2)+i][ec*EC + ee];
                #pragma unroll
                for (int j = 0; j < 4; ++j) {
                    float4 k4 = *(const float4*)&kv[lane + (j<<6)][ee];
                    #pragma unroll
                    for (int i = 0; i < 4; ++i) {
                        sacc[i][j] = fmaf(q4[i].x, k4.x, sacc[i][j]);
                        sacc[i][j] = fmaf(q4[i].y, k4.y, sacc[i][j]);
                        sacc[i][j] = fmaf(q4[i].z, k4.z, sacc[i][j]);
                        sacc[i][j] = fmaf(q4[i].w, k4.w, sacc[i][j]);
                    }
                }
            }
        }

        float tmax[4];
        #pragma unroll
        for (int i = 0; i < 4; ++i)
            tmax[i] = fmaxf(fmaxf(sacc[i][0], sacc[i][1]), fmaxf(sacc[i][2], sacc[i][3]));
        #pragma unroll
        for (int off = 1; off < 64; off <<= 1) {
            #pragma unroll
            for (int i = 0; i < 4; ++i)
                tmax[i] = fmaxf(tmax[i], __shfl_xor(tmax[i], off, 64));
        }
        float rs[4], fi[4];
        #pragma unroll
        for (int i = 0; i < 4; ++i) {
            float mn = fmaxf(m_reg[i], tmax[i]);
            fi[i] = __expf(m_reg[i] - mn);
            m_reg[i] = mn;
            float r = 0.f;
            #pragma unroll
            for (int j = 0; j < 4; ++j) {
                float p = __expf(sacc[i][j] - mn);
                ps[(w<<2)+i][lane + (j<<6)] = p;
                r += p;
            }
            rs[i] = r;
        }
        #pragma unroll
        for (int off = 1; off < 64; off <<= 1) {
            #pragma unroll
            for (int i = 0; i < 4; ++i)
                rs[i] += __shfl_xor(rs[i], off, 64);
        }
        #pragma unroll
        for (int i = 0; i < 4; ++i)
            l_reg[i] = l_reg[i] * fi[i] + rs[i];
        if (lane == 0) {
            #pragma unroll
            for (int i = 0; i < 4; ++i) {
                f_s[(w<<2)+i] = fi[i];
                l_s[(w<<2)+i] = l_reg[i];
            }
        }
        __syncthreads();

        const float fown = f_s[ow];
        #pragma unroll
        for (int c4 = 0; c4 < NCH; ++c4) {
            oacc[c4].x *= fown; oacc[c4].y *= fown;
            oacc[c4].z *= fown; oacc[c4].w *= fown;
        }
        for (int pc = 0; pc < NCH; ++pc) {
            __syncthreads();
            {
                const int rr = t >> 4;
                const int cc = (t & 15) << 2;
                #pragma unroll
                for (int m = 0; m < 16; ++m) {
                    float4 v4 = *(const float4*)&vsrc[(kr0 + rr + (m<<4))*Ee + pc*EC + cc];
                    *(float4*)&kv[rr + (m<<4)][cc] = v4;
                }
            }
            __syncthreads();
            float4 acc = oacc[pc];
            #pragma unroll 4
            for (int tj0 = 0; tj0 < TK; tj0 += 4) {
                float4 p4 = *(const float4*)&ps[ow][tj0];
                float4 v0 = *(const float4*)&kv[tj0+0][oc];
                float4 v1 = *(const float4*)&kv[tj0+1][oc];
                float4 v2 = *(const float4*)&kv[tj0+2][oc];
                float4 v3 = *(const float4*)&kv[tj0+3][oc];
                acc.x = fmaf(p4.x, v0.x, acc.x); acc.y = fmaf(p4.x, v0.y, acc.y);
                acc.z = fmaf(p4.x, v0.z, acc.z); acc.w = fmaf(p4.x, v0.w, acc.w);
                acc.x = fmaf(p4.y, v1.x, acc.x); acc.y = fmaf(p4.y, v1.y, acc.y);
                acc.z = fmaf(p4.y, v1.z, acc.z); acc.w = fmaf(p4.y, v1.w, acc.w);
                acc.x = fmaf(p4.z, v2.x, acc.x); acc.y = fmaf(p4.z, v2.y, acc.y);
                acc.z = fmaf(p4.z, v2.z, acc.z); acc.w = fmaf(p4.z, v2.w, acc.w);
                acc.x = fmaf(p4.w, v3.x, acc.x); acc.y = fmaf(p4.w, v3.y, acc.y);
                acc.z = fmaf(p4.w, v3.z, acc.z); acc.w = fmaf(p4.w, v3.w, acc.w);
            }
            oacc[pc] = acc;
        }
    }

    __syncthreads();
    const float linv = 1.0f / l_s[ow];
    #pragma unroll
    for (int c4 = 0; c4 < NCH; ++c4) {
        float4 o = oacc[c4];
        o.x *= linv; o.y *= linv; o.z *= linv; o.w *= linv;
        *(float4*)&out[(q0 + ow)*Ee + oc + (c4 << 6)] = o;
    }
}

// ================================================================ launch
extern "C" void kernel_launch(void* const* d_in, const int* in_sizes, int n_in,
                              void* d_out, int out_size, void* d_ws, size_t ws_size,
                              hipStream_t stream)
{
    (void)in_sizes; (void)n_in; (void)out_size;
    const float* x  = (const float*)d_in[0];
    const float* Wq = (const float*)d_in[1];
    const float* bq = (const float*)d_in[2];
    const float* Wk = (const float*)d_in[3];
    const float* bk = (const float*)d_in[4];
    const float* Wv = (const float*)d_in[5];
    const float* bv = (const float*)d_in[6];
    float* out = (float*)d_out;

    // fast-path workspace layout (bytes):
    //   [0, 32M)        : Sbuf (4096 rows x 2048 fp32) per 2-batch chunk; P fp16 in-place
    //   [32M, 42M)      : W planes (Wqh,Wql,Wkh,Wkl,Wvh; 1024x1024 fp16 each)
    //   [42M, 170M)     : qh, ql, kh, kl (16384x1024 fp16 each)
    //   [170M, 202M)    : vT (8 x 1024 x 2048 fp16)
    // xh/xl (16384x1024 fp16 each = 64 MB) live in d_out as scratch; pv_gemm
    // fully overwrites d_out afterwards (deterministic across replays).
    const size_t S_OFF  = 0;
    const size_t W_OFF  = 33554432ull;
    const size_t WPL    = 2097152ull;       // bytes per W plane
    const size_t Q_OFF  = W_OFF + 5 * WPL;  // 44040192
    const size_t QPL    = 33554432ull;      // bytes per q/k plane
    const size_t VT_OFF = Q_OFF + 4 * QPL;  // 178257920
    const size_t NEED   = VT_OFF + 33554432ull;  // 211812352

    if (ws_size >= NEED) {
        float* Sbuf = (float*)((char*)d_ws + S_OFF);
        f16* Wqh = (f16*)((char*)d_ws + W_OFF);
        f16* Wql = Wqh + 1048576;
        f16* Wkh = Wqh + 2 * 1048576;
        f16* Wkl = Wqh + 3 * 1048576;
        f16* Wvh = Wqh + 4 * 1048576;
        f16* qh = (f16*)((char*)d_ws + Q_OFF);
        f16* ql = qh + 16777216;
        f16* kh = qh + 2 * 16777216;
        f16* kl = qh + 3 * 16777216;
        f16* vT = (f16*)((char*)d_ws + VT_OFF);
        f16* xh = (f16*)d_out;                 // 32 MB
        f16* xl = xh + (size_t)BSr * Ee;       // 32 MB

        split_weights<<<1024, 256, 0, stream>>>(Wq, Wk, Wv, Wqh, Wql, Wkh, Wkl, Wvh);
        split_x<<<16384, 256, 0, stream>>>(x, xh, xl);
        proj_gemm<<<dim3(24, 128), 256, 0, stream>>>(
            xh, xl, Wqh, Wql, Wkh, Wkl, Wvh, bq, bk, bv, qh, ql, kh, kl, vT);
        for (int c = 0; c < 4; ++c) {
            score_gemm<<<dim3(16, 16, 2), 256, 0, stream>>>(qh, ql, kh, kl, Sbuf, 2 * c);
            softmax_rows<<<4096, 256, 0, stream>>>(Sbuf);
            pv_gemm<<<dim3(8, 16, 2), 256, 0, stream>>>(Sbuf, vT, out, 2 * c);
        }
    } else {
        // legacy fp32 path (needs 128 MB ws)
        float* kbuf = (float*)d_ws;
        float* vbuf = kbuf + (size_t)BSr * Ee;
        dim3 g1(Ee / 64, BSr / 64, 3);
        qkv_gemm<<<g1, 256, 0, stream>>>(x, Wq, bq, Wk, bk, Wv, bv, out, kbuf, vbuf);
        flash_attn<<<dim3(BSr / TQ), 256, 0, stream>>>(out, kbuf, vbuf, out);
    }
}

// Round 5
// 720.342 us; speedup vs baseline: 8.5903x; 1.0764x over previous
//
#include <hip/hip_runtime.h>
#include <math.h>

typedef _Float16 f16;
typedef _Float16 f16x8 __attribute__((ext_vector_type(8)));
typedef _Float16 f16x4 __attribute__((ext_vector_type(4)));
typedef float f32x4v __attribute__((ext_vector_type(4)));

#define Bb 8
#define Ss 2048
#define Ee 1024
#define BSr (Bb*Ss)

// ---------------------------------------------------------------- helpers
__device__ __forceinline__ void gll16(const void* gp, void* lp) {
    // async global->LDS, 16B per lane, LDS dest = wave-uniform base + lane*16
    __builtin_amdgcn_global_load_lds(
        (const __attribute__((address_space(1))) unsigned int*)gp,
        (__attribute__((address_space(3))) unsigned int*)lp,
        16, 0, 0);
}

#define MFMA16(a, b, c) __builtin_amdgcn_mfma_f32_16x16x32_f16((a), (b), (c), 0, 0, 0)
#define SBAR() asm volatile("s_barrier" ::: "memory")
#define WAIT_LGKM0() do { asm volatile("s_waitcnt lgkmcnt(0)" ::: "memory"); __builtin_amdgcn_sched_barrier(0); } while (0)

// ================================================================ split kernels
__global__ __launch_bounds__(256)
void split_weights(const float* __restrict__ Wq, const float* __restrict__ Wk,
                   const float* __restrict__ Wv,
                   f16* __restrict__ Wqh, f16* __restrict__ Wql,
                   f16* __restrict__ Wkh, f16* __restrict__ Wkl,
                   f16* __restrict__ Wvh)
{
    const int i = (blockIdx.x * 256 + threadIdx.x) * 4;
    float4 q = *(const float4*)&Wq[i];
    float4 k = *(const float4*)&Wk[i];
    float4 v = *(const float4*)&Wv[i];
    f16x4 qh4, ql4, kh4, kl4, vh4;
#define SPL(val, h4, l4, idx) { f16 hh = (f16)(val); h4[idx] = hh; l4[idx] = (f16)((val) - (float)hh); }
    SPL(q.x, qh4, ql4, 0) SPL(q.y, qh4, ql4, 1) SPL(q.z, qh4, ql4, 2) SPL(q.w, qh4, ql4, 3)
    SPL(k.x, kh4, kl4, 0) SPL(k.y, kh4, kl4, 1) SPL(k.z, kh4, kl4, 2) SPL(k.w, kh4, kl4, 3)
#undef SPL
    vh4[0] = (f16)v.x; vh4[1] = (f16)v.y; vh4[2] = (f16)v.z; vh4[3] = (f16)v.w;
    *(f16x4*)&Wqh[i] = qh4; *(f16x4*)&Wql[i] = ql4;
    *(f16x4*)&Wkh[i] = kh4; *(f16x4*)&Wkl[i] = kl4;
    *(f16x4*)&Wvh[i] = vh4;
}

__global__ __launch_bounds__(256)
void split_x(const float* __restrict__ x, f16* __restrict__ xh, f16* __restrict__ xl)
{
    const int i = (blockIdx.x * 256 + threadIdx.x) * 4;
    float4 v = *(const float4*)&x[i];
    f16x4 h4, l4;
#define SPL(val, idx) { f16 hh = (f16)(val); h4[idx] = hh; l4[idx] = (f16)((val) - (float)hh); }
    SPL(v.x, 0) SPL(v.y, 1) SPL(v.z, 2) SPL(v.w, 3)
#undef SPL
    *(f16x4*)&xh[i] = h4;
    *(f16x4*)&xl[i] = l4;
}

// ================================================================ 8-phase 256x256 K-loop core
// BM=BN=256, BK=64, 512 threads = 8 waves (wr = w>>2 in {0,1}: 128 M-rows;
// wc = w&3: 64 N-cols). LDS: fragment-ordered 1024B subtiles, [ks][rg] order.
// Wave w stages row/col-groups w and w+8 (srcoff includes w*16*Ee — the
// round-4 bug was omitting this). Per K-tile: 4 phases; staging of tile t+1
// spread 2-gll/phase; counted vmcnt(4) at end of ph1 (curr ks1) and ph3
// (next ks0); vmcnt(0) only on the last tile. All ds_read_b128 are
// contiguous 1024B wave reads (0 bank conflicts).
__device__ __forceinline__ void kloop8(
    const f16* Ap0, const f16* Ap1, const f16* Ap2,
    const f16* Bp0, const f16* Bp1, const f16* Bp2,
    const int npass, f16* As, f16* Bs,
    f32x4v acc[8][4], const int w, const int lane)
{
    const int wr = w >> 2, wc = w & 3;
    // fragment-order per-lane source: wave's row-group base + in-group row + k-chunk
    const int srcoff = (w * 16 + (lane & 15)) * Ee + (lane >> 4) * 8;
    const int lread = lane * 8;                             // 16B per lane
    const int nvt = npass << 4;                             // 16 K-tiles per pass

    // prologue: tile 0 (pass 0) fully into buf 0, drain once
    {
        const f16* gA = Ap0 + srcoff;
        const f16* gB = Bp0 + srcoff;
        f16* lA = As + w * 512;
        f16* lB = Bs + w * 512;
        gll16(gA,                       lA);              // ks0, group w
        gll16(gA + (size_t)8 * 16 * Ee, lA + 8 * 512);    // ks0, group w+8
        gll16(gA + 32,                  lA + 16 * 512);   // ks1, group w
        gll16(gA + 32 + (size_t)8 * 16 * Ee, lA + 24 * 512);
        gll16(gB,                       lB);
        gll16(gB + (size_t)8 * 16 * Ee, lB + 8 * 512);
        gll16(gB + 32,                  lB + 16 * 512);
        gll16(gB + 32 + (size_t)8 * 16 * Ee, lB + 24 * 512);
    }
    asm volatile("s_waitcnt vmcnt(0)" ::: "memory");
    SBAR();

    for (int vt = 0; vt < nvt; ++vt) {
        const int buf = vt & 1;
        const bool more = (vt + 1 < nvt);
        const int tn = (vt + 1) & 15;
        const int pn = (vt + 1) >> 4;
        const f16* An = (pn == 0) ? Ap0 : ((pn == 1) ? Ap1 : Ap2);
        const f16* Bn = (pn == 0) ? Bp0 : ((pn == 1) ? Bp1 : Bp2);
        const f16* An_g = An + tn * 64 + srcoff;
        const f16* Bn_g = Bn + tn * 64 + srcoff;
        f16* As_wr = As + (buf ^ 1) * 16384 + w * 512;
        f16* Bs_wr = Bs + (buf ^ 1) * 16384 + w * 512;
        const f16* As_rd = As + buf * 16384;
        const f16* Bs_rd = Bs + buf * 16384;

        f16x8 fa[8], fb0, fb1;

        // ---------------- ph0: ks0, N-frags 0,1
        #pragma unroll
        for (int i = 0; i < 8; ++i)
            fa[i] = *(const f16x8*)(As_rd + (wr * 8 + i) * 512 + lread);
        fb0 = *(const f16x8*)(Bs_rd + (wc * 4 + 0) * 512 + lread);
        fb1 = *(const f16x8*)(Bs_rd + (wc * 4 + 1) * 512 + lread);
        if (more) {
            gll16(An_g,                       As_wr);            // next ks0 g(w)
            gll16(An_g + (size_t)8 * 16 * Ee, As_wr + 8 * 512);  // next ks0 g(w+8)
        }
        SBAR();
        WAIT_LGKM0();
        __builtin_amdgcn_s_setprio(1);
        #pragma unroll
        for (int i = 0; i < 8; ++i) {
            acc[i][0] = MFMA16(fa[i], fb0, acc[i][0]);
            acc[i][1] = MFMA16(fa[i], fb1, acc[i][1]);
        }
        __builtin_amdgcn_s_setprio(0);
        SBAR();

        // ---------------- ph1: ks0, N-frags 2,3
        fb0 = *(const f16x8*)(Bs_rd + (wc * 4 + 2) * 512 + lread);
        fb1 = *(const f16x8*)(Bs_rd + (wc * 4 + 3) * 512 + lread);
        if (more) {
            gll16(Bn_g,                       Bs_wr);
            gll16(Bn_g + (size_t)8 * 16 * Ee, Bs_wr + 8 * 512);
        }
        SBAR();
        WAIT_LGKM0();
        __builtin_amdgcn_s_setprio(1);
        #pragma unroll
        for (int i = 0; i < 8; ++i) {
            acc[i][2] = MFMA16(fa[i], fb0, acc[i][2]);
            acc[i][3] = MFMA16(fa[i], fb1, acc[i][3]);
        }
        __builtin_amdgcn_s_setprio(0);
        // wait: current tile ks1 landed (4 oldest); last tile -> full drain
        if (more) asm volatile("s_waitcnt vmcnt(4)" ::: "memory");
        else      asm volatile("s_waitcnt vmcnt(0)" ::: "memory");
        SBAR();

        // ---------------- ph2: ks1, N-frags 0,1
        #pragma unroll
        for (int i = 0; i < 8; ++i)
            fa[i] = *(const f16x8*)(As_rd + (16 + wr * 8 + i) * 512 + lread);
        fb0 = *(const f16x8*)(Bs_rd + (16 + wc * 4 + 0) * 512 + lread);
        fb1 = *(const f16x8*)(Bs_rd + (16 + wc * 4 + 1) * 512 + lread);
        if (more) {
            gll16(An_g + 32,                       As_wr + 16 * 512);  // next ks1
            gll16(An_g + 32 + (size_t)8 * 16 * Ee, As_wr + 24 * 512);
        }
        SBAR();
        WAIT_LGKM0();
        __builtin_amdgcn_s_setprio(1);
        #pragma unroll
        for (int i = 0; i < 8; ++i) {
            acc[i][0] = MFMA16(fa[i], fb0, acc[i][0]);
            acc[i][1] = MFMA16(fa[i], fb1, acc[i][1]);
        }
        __builtin_amdgcn_s_setprio(0);
        SBAR();

        // ---------------- ph3: ks1, N-frags 2,3
        fb0 = *(const f16x8*)(Bs_rd + (16 + wc * 4 + 2) * 512 + lread);
        fb1 = *(const f16x8*)(Bs_rd + (16 + wc * 4 + 3) * 512 + lread);
        if (more) {
            gll16(Bn_g + 32,                       Bs_wr + 16 * 512);
            gll16(Bn_g + 32 + (size_t)8 * 16 * Ee, Bs_wr + 24 * 512);
        }
        SBAR();
        WAIT_LGKM0();
        __builtin_amdgcn_s_setprio(1);
        #pragma unroll
        for (int i = 0; i < 8; ++i) {
            acc[i][2] = MFMA16(fa[i], fb0, acc[i][2]);
            acc[i][3] = MFMA16(fa[i], fb1, acc[i][3]);
        }
        __builtin_amdgcn_s_setprio(0);
        // wait: next tile ks0 landed (4 oldest of the 8 staged this tile)
        if (more) asm volatile("s_waitcnt vmcnt(4)" ::: "memory");
        SBAR();
    }
}

// ================================================================ Kernel B: projection (8-phase)
// grid 768 = 12 (4 ncol x 3 z) x 64 row-tiles, XCD-swizzled.
__global__ __launch_bounds__(512, 2)
void proj8(const f16* __restrict__ xh, const f16* __restrict__ xl,
           const f16* __restrict__ Wqh, const f16* __restrict__ Wql,
           const f16* __restrict__ Wkh, const f16* __restrict__ Wkl,
           const f16* __restrict__ Wvh,
           const float* __restrict__ bq, const float* __restrict__ bk,
           const float* __restrict__ bv,
           f16* __restrict__ qh, f16* __restrict__ ql,
           f16* __restrict__ kh, f16* __restrict__ kl,
           f16* __restrict__ vT)
{
    __shared__ f16 As[32768];   // 64 KB: 2 buf x 32 subtiles x 1024B
    __shared__ f16 Bs[32768];

    const int lin = blockIdx.x;
    const int l = (lin & 7) * 96 + (lin >> 3);   // 768/8 = 96
    const int bx12 = l % 12;
    const int by = l / 12;
    const int z = bx12 >> 2;
    const int col0 = (bx12 & 3) * 256;
    const int row0 = by * 256;

    const f16* Wh = (z == 0) ? Wqh : ((z == 1) ? Wkh : Wvh);
    const f16* Wl = (z == 0) ? Wql : Wkl;
    const float* bias = (z == 0) ? bq : ((z == 1) ? bk : bv);
    const int npass = (z == 2) ? 1 : 3;

    const int t = threadIdx.x;
    const int lane = t & 63;
    const int w = t >> 6;
    const int wr = w >> 2, wc = w & 3;

    const f16* Axh = xh + (size_t)row0 * Ee;
    const f16* Axl = xl + (size_t)row0 * Ee;
    const f16* Bwh = Wh + (size_t)col0 * Ee;
    const f16* Bwl = Wl + (size_t)col0 * Ee;

    f32x4v acc[8][4];
    #pragma unroll
    for (int i = 0; i < 8; ++i)
        #pragma unroll
        for (int j = 0; j < 4; ++j) acc[i][j] = (f32x4v)0.f;

    // passes: (xh,Wh), (xh,Wl), (xl,Wh)  [z==2: (xh,Wvh) only]
    kloop8(Axh, Axh, Axl, Bwh, Bwl, Bwh, npass, As, Bs, acc, w, lane);

    if (z < 2) {
        f16* __restrict__ oh = (z == 0) ? qh : kh;
        f16* __restrict__ ol = (z == 0) ? ql : kl;
        #pragma unroll
        for (int i = 0; i < 8; ++i) {
            #pragma unroll
            for (int j = 0; j < 4; ++j) {
                const int col = col0 + wc * 64 + j * 16 + (lane & 15);
                const float b = bias[col];
                #pragma unroll
                for (int r = 0; r < 4; ++r) {
                    const int row = row0 + wr * 128 + i * 16 + (lane >> 4) * 4 + r;
                    const float vv = acc[i][j][r] + b;
                    const f16 hh = (f16)vv;
                    oh[(size_t)row * Ee + col] = hh;
                    ol[(size_t)row * Ee + col] = (f16)(vv - (float)hh);
                }
            }
        }
    } else {
        #pragma unroll
        for (int i = 0; i < 8; ++i) {
            #pragma unroll
            for (int j = 0; j < 4; ++j) {
                const int e = col0 + wc * 64 + j * 16 + (lane & 15);
                const float b = bias[e];
                const int srow = row0 + wr * 128 + i * 16 + (lane >> 4) * 4;
                const int bb = srow >> 11;
                const int s = srow & 2047;
                f16x4 pk;
                #pragma unroll
                for (int r = 0; r < 4; ++r) pk[r] = (f16)(acc[i][j][r] + b);
                *(f16x4*)&vT[((size_t)bb * Ee + e) * Ss + s] = pk;
            }
        }
    }
}

// ================================================================ Kernel C: scores (8-phase)
// grid 64*nb 1D, XCD-swizzled. S = q k^T per batch, 3-pass split, fp32 out.
__global__ __launch_bounds__(512, 2)
void score8(const f16* __restrict__ qh, const f16* __restrict__ ql,
            const f16* __restrict__ kh, const f16* __restrict__ kl,
            float* __restrict__ Sbuf, int batch0)
{
    __shared__ f16 As[32768];
    __shared__ f16 Bs[32768];

    const int lin = blockIdx.x;
    const int cpx = gridDim.x >> 3;
    const int l = (lin & 7) * cpx + (lin >> 3);
    const int bn = l & 7;
    const int bm = (l >> 3) & 7;
    const int zb = l >> 6;
    const int b = batch0 + zb;

    const int t = threadIdx.x;
    const int lane = t & 63;
    const int w = t >> 6;
    const int wr = w >> 2, wc = w & 3;

    const f16* Aq_h = qh + ((size_t)b * Ss + bm * 256) * Ee;
    const f16* Aq_l = ql + ((size_t)b * Ss + bm * 256) * Ee;
    const f16* Bk_h = kh + ((size_t)b * Ss + bn * 256) * Ee;
    const f16* Bk_l = kl + ((size_t)b * Ss + bn * 256) * Ee;

    f32x4v acc[8][4];
    #pragma unroll
    for (int i = 0; i < 8; ++i)
        #pragma unroll
        for (int j = 0; j < 4; ++j) acc[i][j] = (f32x4v)0.f;

    // passes: (qh,kh), (qh,kl), (ql,kh)
    kloop8(Aq_h, Aq_h, Aq_l, Bk_h, Bk_l, Bk_h, 3, As, Bs, acc, w, lane);

    #pragma unroll
    for (int i = 0; i < 8; ++i) {
        #pragma unroll
        for (int j = 0; j < 4; ++j) {
            const int col = bn * 256 + wc * 64 + j * 16 + (lane & 15);
            #pragma unroll
            for (int r = 0; r < 4; ++r) {
                const int row = zb * Ss + bm * 256 + wr * 128 + i * 16 + (lane >> 4) * 4 + r;
                Sbuf[(size_t)row * 2048 + col] = acc[i][j][r];
            }
        }
    }
}

// ================================================================ Kernel D: row softmax
__global__ __launch_bounds__(256)
void softmax_rows(float* __restrict__ Sbuf)
{
    __shared__ float red[8];
    const int t = threadIdx.x;
    const int w = t >> 6;
    float* Srow = Sbuf + (size_t)blockIdx.x * 2048;

    float4 a = *(const float4*)&Srow[t * 8];
    float4 c = *(const float4*)&Srow[t * 8 + 4];
    float v[8] = {a.x, a.y, a.z, a.w, c.x, c.y, c.z, c.w};

    float m = v[0];
    #pragma unroll
    for (int i = 1; i < 8; ++i) m = fmaxf(m, v[i]);
    #pragma unroll
    for (int off = 1; off < 64; off <<= 1) m = fmaxf(m, __shfl_xor(m, off, 64));
    if ((t & 63) == 0) red[w] = m;
    __syncthreads();
    m = fmaxf(fmaxf(red[0], red[1]), fmaxf(red[2], red[3]));

    float e[8], s = 0.f;
    #pragma unroll
    for (int i = 0; i < 8; ++i) { e[i] = __expf(v[i] - m); s += e[i]; }
    #pragma unroll
    for (int off = 1; off < 64; off <<= 1) s += __shfl_xor(s, off, 64);
    if ((t & 63) == 0) red[4 + w] = s;
    __syncthreads();
    s = red[4] + red[5] + red[6] + red[7];

    const float inv = 1.0f / s;
    f16x8 pk;
    #pragma unroll
    for (int i = 0; i < 8; ++i) pk[i] = (f16)(e[i] * inv);
    *(f16x8*)(((f16*)Srow) + t * 8) = pk;
}

// ================================================================ Kernel E: O = P * v (128^2 m97-style)
__global__ __launch_bounds__(256)
void pv_gemm(const float* __restrict__ Sbuf, const f16* __restrict__ vT,
             float* __restrict__ out, int batch0)
{
    __shared__ f16 Pt[128][32];
    __shared__ f16 Vt[128][32];

    const int zb = blockIdx.z;
    const int b = batch0 + zb;
    const int bm = blockIdx.y;
    const int bn = blockIdx.x;

    const int t = threadIdx.x;
    const int lane = t & 63;
    const int w = t >> 6;
    const int wr = w >> 1, wc = w & 1;
    const int lr = lane & 15;
    const int kq = (lane >> 4) << 3;

    const int rS = w * 32 + (lane >> 2);
    const int eS = (lane & 3) * 8;

    const f16* Pbase = (const f16*)Sbuf;
    const f16* gA = Pbase + ((size_t)(zb * Ss + bm * 128 + rS)) * 4096 + eS;
    const f16* gB = vT + ((size_t)b * Ee + bn * 128 + rS) * Ss + eS;

    f32x4v acc[4][4];
    #pragma unroll
    for (int i = 0; i < 4; ++i)
        #pragma unroll
        for (int j = 0; j < 4; ++j) acc[i][j] = (f32x4v)0.f;

    for (int k0 = 0; k0 < Ss; k0 += 32) {
        __syncthreads();
        #pragma unroll
        for (int c = 0; c < 2; ++c) {
            const int lo = w * 1024 + c * 512;
            gll16(gA + (size_t)c * 16 * 4096 + k0, &Pt[0][0] + lo);
            gll16(gB + (size_t)c * 16 * Ss + k0,   &Vt[0][0] + lo);
        }
        __syncthreads();

        f16x8 fa[4], fb[4];
        #pragma unroll
        for (int i = 0; i < 4; ++i) {
            fa[i] = *(const f16x8*)&Pt[wr * 64 + i * 16 + lr][kq];
            fb[i] = *(const f16x8*)&Vt[wc * 64 + i * 16 + lr][kq];
        }
        #pragma unroll
        for (int i = 0; i < 4; ++i)
            #pragma unroll
            for (int j = 0; j < 4; ++j)
                acc[i][j] = MFMA16(fa[i], fb[j], acc[i][j]);
    }

    #pragma unroll
    for (int i = 0; i < 4; ++i) {
        #pragma unroll
        for (int j = 0; j < 4; ++j) {
            const int col = bn * 128 + wc * 64 + j * 16 + lr;
            #pragma unroll
            for (int r = 0; r < 4; ++r) {
                const int row = bm * 128 + wr * 64 + i * 16 + (lane >> 4) * 4 + r;
                out[((size_t)b * Ss + row) * Ee + col] = acc[i][j][r];
            }
        }
    }
}

// ================================================================ legacy path (fp32 fallback)
#define TQ 16
#define TK 256
#define EC 64
#define NCH (Ee/EC)
#define NT  (Ss/TK)

__global__ __launch_bounds__(256)
void qkv_gemm(const float* __restrict__ x,
              const float* __restrict__ Wq, const float* __restrict__ bq,
              const float* __restrict__ Wk, const float* __restrict__ bk,
              const float* __restrict__ Wv, const float* __restrict__ bv,
              float* __restrict__ oq, float* __restrict__ ok, float* __restrict__ ov)
{
    __shared__ float Xs[64][17];
    __shared__ float Ws[64][17];
    const int t = threadIdx.x;
    const int z = blockIdx.z;
    const float* __restrict__ W    = (z == 0) ? Wq : ((z == 1) ? Wk : Wv);
    const float* __restrict__ bias = (z == 0) ? bq : ((z == 1) ? bk : bv);
    float* __restrict__ out        = (z == 0) ? oq : ((z == 1) ? ok : ov);

    const int row0 = blockIdx.y << 6;
    const int col0 = blockIdx.x << 6;
    const int ti = t >> 4;
    const int tj = t & 15;
    const int lr = t >> 2;
    const int lc = (t & 3) << 2;

    float acc[4][4];
    #pragma unroll
    for (int i = 0; i < 4; ++i)
        #pragma unroll
        for (int j = 0; j < 4; ++j) acc[i][j] = 0.f;

    for (int e0 = 0; e0 < Ee; e0 += 16) {
        __syncthreads();
        {
            float4 xv = *(const float4*)&x[(row0 + lr)*Ee + e0 + lc];
            float4 wv = *(const float4*)&W[(col0 + lr)*Ee + e0 + lc];
            Xs[lr][lc]   = xv.x; Xs[lr][lc+1] = xv.y; Xs[lr][lc+2] = xv.z; Xs[lr][lc+3] = xv.w;
            Ws[lr][lc]   = wv.x; Ws[lr][lc+1] = wv.y; Ws[lr][lc+2] = wv.z; Ws[lr][lc+3] = wv.w;
        }
        __syncthreads();
        #pragma unroll
        for (int ee = 0; ee < 16; ++ee) {
            float xa[4], wb[4];
            #pragma unroll
            for (int i = 0; i < 4; ++i) xa[i] = Xs[(ti<<2)+i][ee];
            #pragma unroll
            for (int j = 0; j < 4; ++j) wb[j] = Ws[(tj<<2)+j][ee];
            #pragma unroll
            for (int i = 0; i < 4; ++i)
                #pragma unroll
                for (int j = 0; j < 4; ++j)
                    acc[i][j] = fmaf(xa[i], wb[j], acc[i][j]);
        }
    }

    const float4 b4 = *(const float4*)&bias[col0 + (tj<<2)];
    #pragma unroll
    for (int i = 0; i < 4; ++i) {
        float4 o;
        o.x = acc[i][0] + b4.x;
        o.y = acc[i][1] + b4.y;
        o.z = acc[i][2] + b4.z;
        o.w = acc[i][3] + b4.w;
        *(float4*)&out[(row0 + (ti<<2) + i)*Ee + col0 + (tj<<2)] = o;
    }
}

__global__ __launch_bounds__(256)
void flash_attn(const float* __restrict__ qsrc,
                const float* __restrict__ ksrc,
                const float* __restrict__ vsrc,
                float* __restrict__ out)
{
    __shared__ float qs[TQ][1028];
    __shared__ float kv[TK][68];
    __shared__ float ps[TQ][260];
    __shared__ float f_s[TQ];
    __shared__ float l_s[TQ];

    const int t = threadIdx.x;
    const int lane = t & 63;
    const int w = t >> 6;
    const int q0 = blockIdx.x * TQ;
    const int kb = (q0 / Ss) * Ss;

    {
        const int r = t >> 4;
        const int c0 = (t & 15) << 2;
        #pragma unroll
        for (int m = 0; m < 16; ++m) {
            float4 v4 = *(const float4*)&qsrc[(q0 + r)*Ee + c0 + (m << 6)];
            *(float4*)&qs[r][c0 + (m << 6)] = v4;
        }
    }

    float4 oacc[NCH];
    #pragma unroll
    for (int i = 0; i < NCH; ++i) oacc[i] = make_float4(0.f, 0.f, 0.f, 0.f);
    float m_reg[4], l_reg[4];
    #pragma unroll
    for (int i = 0; i < 4; ++i) { m_reg[i] = -INFINITY; l_reg[i] = 0.f; }

    const int ow = t >> 4;
    const int oc = (t & 15) << 2;

    for (int kt = 0; kt < NT; ++kt) {
        const int kr0 = kb + kt * TK;

        float sacc[4][4];
        #pragma unroll
        for (int i = 0; i < 4; ++i)
            #pragma unroll
            for (int j = 0; j < 4; ++j) sacc[i][j] = 0.f;

        for (int ec = 0; ec < NCH; ++ec) {
            __syncthreads();
            {
                const int rr = t >> 4;
                const int cc = (t & 15) << 2;
                #pragma unroll
                for (int m = 0; m < 16; ++m) {
                    float4 v4 = *(const float4*)&ksrc[(kr0 + rr + (m<<4))*Ee + ec*EC + cc];
                    *(float4*)&kv[rr + (m<<4)][cc] = v4;
                }
            }
            __syncthreads();
            #pragma unroll 4
            for (int ee = 0; ee < EC; ee += 4) {
                float4 q4[4];
                #pragma unroll
                for (int i = 0; i < 4; ++i)
                    q4[i] = *(const float4*)&qs[(w<<2)+i][ec*EC + ee];
                #pragma unroll
                for (int j = 0; j < 4; ++j) {
                    float4 k4 = *(const float4*)&kv[lane + (j<<6)][ee];
                    #pragma unroll
                    for (int i = 0; i < 4; ++i) {
                        sacc[i][j] = fmaf(q4[i].x, k4.x, sacc[i][j]);
                        sacc[i][j] = fmaf(q4[i].y, k4.y, sacc[i][j]);
                        sacc[i][j] = fmaf(q4[i].z, k4.z, sacc[i][j]);
                        sacc[i][j] = fmaf(q4[i].w, k4.w, sacc[i][j]);
                    }
                }
            }
        }

        float tmax[4];
        #pragma unroll
        for (int i = 0; i < 4; ++i)
            tmax[i] = fmaxf(fmaxf(sacc[i][0], sacc[i][1]), fmaxf(sacc[i][2], sacc[i][3]));
        #pragma unroll
        for (int off = 1; off < 64; off <<= 1) {
            #pragma unroll
            for (int i = 0; i < 4; ++i)
                tmax[i] = fmaxf(tmax[i], __shfl_xor(tmax[i], off, 64));
        }
        float rs[4], fi[4];
        #pragma unroll
        for (int i = 0; i < 4; ++i) {
            float mn = fmaxf(m_reg[i], tmax[i]);
            fi[i] = __expf(m_reg[i] - mn);
            m_reg[i] = mn;
            float r = 0.f;
            #pragma unroll
            for (int j = 0; j < 4; ++j) {
                float p = __expf(sacc[i][j] - mn);
                ps[(w<<2)+i][lane + (j<<6)] = p;
                r += p;
            }
            rs[i] = r;
        }
        #pragma unroll
        for (int off = 1; off < 64; off <<= 1) {
            #pragma unroll
            for (int i = 0; i < 4; ++i)
                rs[i] += __shfl_xor(rs[i], off, 64);
        }
        #pragma unroll
        for (int i = 0; i < 4; ++i)
            l_reg[i] = l_reg[i] * fi[i] + rs[i];
        if (lane == 0) {
            #pragma unroll
            for (int i = 0; i < 4; ++i) {
                f_s[(w<<2)+i] = fi[i];
                l_s[(w<<2)+i] = l_reg[i];
            }
        }
        __syncthreads();

        const float fown = f_s[ow];
        #pragma unroll
        for (int c4 = 0; c4 < NCH; ++c4) {
            oacc[c4].x *= fown; oacc[c4].y *= fown;
            oacc[c4].z *= fown; oacc[c4].w *= fown;
        }
        for (int pc = 0; pc < NCH; ++pc) {
            __syncthreads();
            {
                const int rr = t >> 4;
                const int cc = (t & 15) << 2;
                #pragma unroll
                for (int m = 0; m < 16; ++m) {
                    float4 v4 = *(const float4*)&vsrc[(kr0 + rr + (m<<4))*Ee + pc*EC + cc];
                    *(float4*)&kv[rr + (m<<4)][cc] = v4;
                }
            }
            __syncthreads();
            float4 acc = oacc[pc];
            #pragma unroll 4
            for (int tj0 = 0; tj0 < TK; tj0 += 4) {
                float4 p4 = *(const float4*)&ps[ow][tj0];
                float4 v0 = *(const float4*)&kv[tj0+0][oc];
                float4 v1 = *(const float4*)&kv[tj0+1][oc];
                float4 v2 = *(const float4*)&kv[tj0+2][oc];
                float4 v3 = *(const float4*)&kv[tj0+3][oc];
                acc.x = fmaf(p4.x, v0.x, acc.x); acc.y = fmaf(p4.x, v0.y, acc.y);
                acc.z = fmaf(p4.x, v0.z, acc.z); acc.w = fmaf(p4.x, v0.w, acc.w);
                acc.x = fmaf(p4.y, v1.x, acc.x); acc.y = fmaf(p4.y, v1.y, acc.y);
                acc.z = fmaf(p4.y, v1.z, acc.z); acc.w = fmaf(p4.y, v1.w, acc.w);
                acc.x = fmaf(p4.z, v2.x, acc.x); acc.y = fmaf(p4.z, v2.y, acc.y);
                acc.z = fmaf(p4.z, v2.z, acc.z); acc.w = fmaf(p4.z, v2.w, acc.w);
                acc.x = fmaf(p4.w, v3.x, acc.x); acc.y = fmaf(p4.w, v3.y, acc.y);
                acc.z = fmaf(p4.w, v3.z, acc.z); acc.w = fmaf(p4.w, v3.w, acc.w);
            }
            oacc[pc] = acc;
        }
    }

    __syncthreads();
    const float linv = 1.0f / l_s[ow];
    #pragma unroll
    for (int c4 = 0; c4 < NCH; ++c4) {
        float4 o = oacc[c4];
        o.x *= linv; o.y *= linv; o.z *= linv; o.w *= linv;
        *(float4*)&out[(q0 + ow)*Ee + oc + (c4 << 6)] = o;
    }
}

// ================================================================ launch
extern "C" void kernel_launch(void* const* d_in, const int* in_sizes, int n_in,
                              void* d_out, int out_size, void* d_ws, size_t ws_size,
                              hipStream_t stream)
{
    (void)in_sizes; (void)n_in; (void)out_size;
    const float* x  = (const float*)d_in[0];
    const float* Wq = (const float*)d_in[1];
    const float* bq = (const float*)d_in[2];
    const float* Wk = (const float*)d_in[3];
    const float* bk = (const float*)d_in[4];
    const float* Wv = (const float*)d_in[5];
    const float* bv = (const float*)d_in[6];
    float* out = (float*)d_out;

    const size_t WPL  = 2097152ull;       // bytes per W plane
    const size_t QPL  = 33554432ull;      // bytes per q/k plane
    const size_t S4   = 67108864ull;      // Sbuf for 4-batch chunks
    const size_t S2   = 33554432ull;      // Sbuf for 2-batch chunks
    const size_t NEED4 = S4 + 5 * WPL + 4 * QPL + 33554432ull;  // 245366784
    const size_t NEED2 = S2 + 5 * WPL + 4 * QPL + 33554432ull;  // 211812352

    if (ws_size >= NEED2) {
        const int nb = (ws_size >= NEED4) ? 4 : 2;
        const size_t sbytes = (nb == 4) ? S4 : S2;
        float* Sbuf = (float*)d_ws;
        f16* Wqh = (f16*)((char*)d_ws + sbytes);
        f16* Wql = Wqh + 1048576;
        f16* Wkh = Wqh + 2 * 1048576;
        f16* Wkl = Wqh + 3 * 1048576;
        f16* Wvh = Wqh + 4 * 1048576;
        f16* qh = (f16*)((char*)d_ws + sbytes + 5 * WPL);
        f16* ql = qh + 16777216;
        f16* kh = qh + 2 * 16777216;
        f16* kl = qh + 3 * 16777216;
        f16* vT = (f16*)((char*)d_ws + sbytes + 5 * WPL + 4 * QPL);
        f16* xh = (f16*)d_out;                 // 32 MB scratch (overwritten by pv)
        f16* xl = xh + (size_t)BSr * Ee;       // 32 MB

        split_weights<<<1024, 256, 0, stream>>>(Wq, Wk, Wv, Wqh, Wql, Wkh, Wkl, Wvh);
        split_x<<<16384, 256, 0, stream>>>(x, xh, xl);
        proj8<<<768, 512, 0, stream>>>(
            xh, xl, Wqh, Wql, Wkh, Wkl, Wvh, bq, bk, bv, qh, ql, kh, kl, vT);
        for (int c = 0; c < 8 / nb; ++c) {
            score8<<<64 * nb, 512, 0, stream>>>(qh, ql, kh, kl, Sbuf, nb * c);
            softmax_rows<<<nb * 2048, 256, 0, stream>>>(Sbuf);
            pv_gemm<<<dim3(8, 16, nb), 256, 0, stream>>>(Sbuf, vT, out, nb * c);
        }
    } else {
        // legacy fp32 path (needs 128 MB ws)
        float* kbuf = (float*)d_ws;
        float* vbuf = kbuf + (size_t)BSr * Ee;
        dim3 g1(Ee / 64, BSr / 64, 3);
        qkv_gemm<<<g1, 256, 0, stream>>>(x, Wq, bq, Wk, bk, Wv, bv, out, kbuf, vbuf);
        flash_attn<<<dim3(BSr / TQ), 256, 0, stream>>>(out, kbuf, vbuf, out);
    }
}